// Round 1
// baseline (4166.570 us; speedup 1.0000x reference)
//
#include <hip/hip_runtime.h>
#include <math.h>

#define B_ 8
#define T_ 512
#define FEAT_ 128
#define TP 256          // T' after frontend
#define DM 128          // d_model
#define DI 256          // d_inner
#define DS 16           // d_state
#define DTR 8
#define NL 10

__device__ __forceinline__ float fsilu(float x){ return x / (1.f + __expf(-x)); }
__device__ __forceinline__ float fsoftplus(float x){ return (x > 20.f) ? x : log1pf(__expf(x)); }

// ---------- transpose x [8,512,128] -> xT [8,128,512]
__global__ void k_transpose_x(const float* __restrict__ x, float* __restrict__ xT){
  int idx = blockIdx.x*256 + threadIdx.x;
  if(idx >= B_*FEAT_*T_) return;
  int t = idx % T_; int f = (idx/T_) % FEAT_; int b = idx/(T_*FEAT_);
  xT[idx] = x[((size_t)b*T_ + t)*FEAT_ + f];
}

// ---------- direct 3x3 SAME conv + folded BN + SiLU.
// in [B,CIN,H,W], w [CO,CIN,3,3]. block = W/4 threads; grid = B*(CO/2)*H.
// each thread: 2 output channels x 4 consecutive j.
__global__ void k_conv3x3(const float* __restrict__ in, const float* __restrict__ w,
                          const float* __restrict__ cb, const float* __restrict__ bs,
                          const float* __restrict__ bb, float* __restrict__ out,
                          int CIN, int CO, int H, int W){
  int jg = threadIdx.x;
  int j0 = jg*4;
  int i  = blockIdx.x % H;
  int cp = (blockIdx.x / H) % (CO>>1);
  int b  = blockIdx.x / (H*(CO>>1));
  int co0 = cp*2;
  float a0[4] = {0.f,0.f,0.f,0.f};
  float a1[4] = {0.f,0.f,0.f,0.f};
  const float* w0base = w + (size_t)co0*CIN*9;
  const float* w1base = w0base + (size_t)CIN*9;
  for(int ci=0; ci<CIN; ci++){
    const float* ip = in + ((size_t)(b*CIN+ci)*H)*W;
    #pragma unroll
    for(int kh=0; kh<3; kh++){
      int ii = i + kh - 1;
      if(ii < 0 || ii >= H) continue;
      float v[6];
      #pragma unroll
      for(int c=0;c<6;c++){
        int jj = j0 - 1 + c;
        v[c] = (jj>=0 && jj<W) ? ip[(size_t)ii*W + jj] : 0.f;
      }
      const float* wp0 = w0base + ci*9 + kh*3;
      const float* wp1 = w1base + ci*9 + kh*3;
      #pragma unroll
      for(int kw=0;kw<3;kw++){
        float x0 = wp0[kw], x1 = wp1[kw];
        #pragma unroll
        for(int u=0;u<4;u++){
          a0[u] = fmaf(x0, v[u+kw], a0[u]);
          a1[u] = fmaf(x1, v[u+kw], a1[u]);
        }
      }
    }
  }
  {
    float s = bs[co0], bias = cb[co0]*s + bb[co0];
    float* op = out + (((size_t)(b*CO+co0)*H + i)*W + j0);
    #pragma unroll
    for(int u=0;u<4;u++) op[u] = fsilu(a0[u]*s + bias);
  }
  {
    float s = bs[co0+1], bias = cb[co0+1]*s + bb[co0+1];
    float* op = out + (((size_t)(b*CO+co0+1)*H + i)*W + j0);
    #pragma unroll
    for(int u=0;u<4;u++) op[u] = fsilu(a1[u]*s + bias);
  }
}

// ---------- 2x2 max pool stride 2
__global__ void k_pool2x2(const float* __restrict__ in, float* __restrict__ out,
                          int C, int Hi, int Wi){
  int Ho = Hi>>1, Wo = Wi>>1;
  int total = B_*C*Ho*Wo;
  int idx = blockIdx.x*256 + threadIdx.x;
  if(idx >= total) return;
  int j = idx % Wo; int i = (idx/Wo)%Ho; int c = (idx/(Wo*Ho))%C; int b = idx/(Wo*Ho*C);
  const float* p = in + (((size_t)(b*C+c)*Hi + 2*i)*Wi + 2*j);
  out[idx] = fmaxf(fmaxf(p[0], p[1]), fmaxf(p[Wi], p[Wi+1]));
}

// ---------- (2,1) max pool + transpose to [b*256+t][c*32+hh]  (proj GEMM A-matrix)
__global__ void k_pool2x1t(const float* __restrict__ in, float* __restrict__ out){
  // in: [8,64,64,256]
  int idx = blockIdx.x*256 + threadIdx.x; // 8*256*2048
  if(idx >= B_*TP*2048) return;
  int f = idx & 2047; int t = (idx>>11) & (TP-1); int b = idx >> 19;
  int c = f >> 5, hh = f & 31;
  const float* p = in + (((size_t)(b*64+c)*64 + 2*hh)*256 + t);
  out[idx] = fmaxf(p[0], p[256]);
}

// ---------- generic fp32 GEMM: C[M,N] = act(A[M,K(lda)] @ W[N,K]^T + bias) (+residual)
// block tile 64x64, BK=16, 256 threads, 4x4 per thread.
template<int ACT, int RES>  // ACT: 0 none, 1 silu, 2 softplus
__global__ __launch_bounds__(256) void k_gemm(const float* __restrict__ A, int lda,
              const float* __restrict__ W, const float* __restrict__ bias,
              float* __restrict__ C, int M, int N, int K){
  __shared__ __align__(16) float As[16][64];
  __shared__ __align__(16) float Ws[16][64];
  int tid = threadIdx.x;
  int n0 = blockIdx.x*64, m0 = blockIdx.y*64;
  int ra = tid>>2, ca = (tid&3)*4;
  int tx = tid & 15, ty = tid >> 4;
  float acc[4][4] = {};
  for(int k0=0; k0<K; k0+=16){
    int k = k0 + ca;
    {
      int m = m0 + ra;
      if(m < M && (k+3) < K){
        float4 v = *(const float4*)(A + (size_t)m*lda + k);
        As[ca+0][ra]=v.x; As[ca+1][ra]=v.y; As[ca+2][ra]=v.z; As[ca+3][ra]=v.w;
      } else {
        #pragma unroll
        for(int c=0;c<4;c++) As[ca+c][ra] = (m<M && (k+c)<K) ? A[(size_t)m*lda + k + c] : 0.f;
      }
      int n = n0 + ra;
      if(n < N && (k+3) < K){
        float4 v = *(const float4*)(W + (size_t)n*K + k);
        Ws[ca+0][ra]=v.x; Ws[ca+1][ra]=v.y; Ws[ca+2][ra]=v.z; Ws[ca+3][ra]=v.w;
      } else {
        #pragma unroll
        for(int c=0;c<4;c++) Ws[ca+c][ra] = (n<N && (k+c)<K) ? W[(size_t)n*K + k + c] : 0.f;
      }
    }
    __syncthreads();
    #pragma unroll
    for(int kk=0; kk<16; kk++){
      float4 a4 = *(const float4*)&As[kk][ty*4];
      float4 w4 = *(const float4*)&Ws[kk][tx*4];
      float av[4] = {a4.x,a4.y,a4.z,a4.w};
      float wv[4] = {w4.x,w4.y,w4.z,w4.w};
      #pragma unroll
      for(int iu=0; iu<4; iu++)
        #pragma unroll
        for(int ju=0; ju<4; ju++)
          acc[iu][ju] = fmaf(av[iu], wv[ju], acc[iu][ju]);
    }
    __syncthreads();
  }
  #pragma unroll
  for(int iu=0; iu<4; iu++){
    int m = m0 + ty*4 + iu;
    if(m >= M) continue;
    #pragma unroll
    for(int ju=0; ju<4; ju++){
      int n = n0 + tx*4 + ju;
      if(n >= N) continue;
      float v = acc[iu][ju];
      if(bias) v += bias[n];
      if(ACT==1) v = fsilu(v);
      else if(ACT==2) v = fsoftplus(v);
      size_t o = (size_t)m*N + n;
      if(RES) v += C[o];
      C[o] = v;
    }
  }
}

// ---------- LayerNorm over last dim (128), optional SiLU. 1 wave per row.
template<int SILU>
__global__ void k_ln(const float* __restrict__ in, const float* __restrict__ g,
                     const float* __restrict__ b, float* __restrict__ out){
  int row = blockIdx.x;
  int t = threadIdx.x; // 64
  const float* p = in + (size_t)row*DM;
  float v0 = p[t], v1 = p[t+64];
  float s = v0 + v1;
  #pragma unroll
  for(int m=32;m>=1;m>>=1) s += __shfl_xor(s, m);
  float mean = s * (1.f/128.f);
  float e0 = v0-mean, e1 = v1-mean;
  float q = e0*e0 + e1*e1;
  #pragma unroll
  for(int m=32;m>=1;m>>=1) q += __shfl_xor(q, m);
  float inv = rsqrtf(q*(1.f/128.f) + 1e-5f);
  float o0 = e0*inv*g[t] + b[t];
  float o1 = e1*inv*g[t+64] + b[t+64];
  if(SILU){ o0 = fsilu(o0); o1 = fsilu(o1); }
  float* po = out + (size_t)row*DM;
  po[t] = o0; po[t+64] = o1;
}

// ---------- causal depthwise conv1d (width 4, left-pad 3) + SiLU
__global__ void k_dwconv(const float* __restrict__ xz, const float* __restrict__ cw,
                         const float* __restrict__ cb, float* __restrict__ xc){
  int idx = blockIdx.x*256 + threadIdx.x;
  if(idx >= B_*TP*DI) return;
  int d = idx & (DI-1);
  int t = (idx >> 8) & (TP-1);
  int b = idx >> 16;
  const float* base = xz + ((size_t)(b*TP))*512 + d;
  float acc = cb[d];
  #pragma unroll
  for(int k=0;k<4;k++){
    int tt = t - 3 + k;
    if(tt >= 0) acc = fmaf(cw[d*4+k], base[(size_t)tt*512], acc);
  }
  xc[idx] = fsilu(acc);
}

// ---------- selective scan + D skip + z gate.
// grid = 8(b) * 32(d-blocks of 8), block = 128 (8 d-groups x 16 states).
// All t-series operands staged in LDS up front; 16-lane shuffle reduce for C-dot.
__global__ __launch_bounds__(128) void k_scan(const float* __restrict__ dtb,
      const float* __restrict__ xc, const float* __restrict__ xz,
      const float* __restrict__ dbc, const float* __restrict__ A_log,
      const float* __restrict__ Dp, float* __restrict__ y){
  __shared__ float dt_s[TP*8], xc_s[TP*8], z_s[TP*8];
  __shared__ float Bs[TP*16], Cs[TP*16];
  int tid = threadIdx.x;
  int dblk = blockIdx.x & 31;
  int b = blockIdx.x >> 5;
  int d0 = dblk*8;
  size_t rbase = (size_t)b*TP;
  for(int u=tid; u<TP*8; u+=128){
    int tt = u>>3, gg = u&7;
    size_t r = rbase + tt;
    dt_s[u] = dtb[r*DI + d0 + gg];
    xc_s[u] = xc [r*DI + d0 + gg];
    z_s[u]  = xz [r*512 + DI + d0 + gg];
  }
  for(int u=tid; u<TP*16; u+=128){
    int tt = u>>4, nn = u&15;
    size_t r = rbase + tt;
    Bs[u] = dbc[r*40 + 8  + nn];
    Cs[u] = dbc[r*40 + 24 + nn];
  }
  __syncthreads();
  int g = tid >> 4, n = tid & 15;
  int d = d0 + g;
  float An = -__expf(A_log[d*DS + n]);
  float Dpd = Dp[d];
  float h = 0.f;
  for(int t=0;t<TP;t++){
    float dtv = dt_s[t*8+g];
    float xcv = xc_s[t*8+g];
    float Bv  = Bs[t*16+n];
    float Cv  = Cs[t*16+n];
    float e = __expf(dtv*An);
    h = fmaf(e, h, dtv*xcv*Bv);
    float p = h*Cv;
    p += __shfl_xor(p,1); p += __shfl_xor(p,2);
    p += __shfl_xor(p,4); p += __shfl_xor(p,8);
    if(n==0){
      float zv = z_s[t*8+g];
      z_s[t*8+g] = (p + Dpd*xcv) * fsilu(zv);
    }
  }
  __syncthreads();
  for(int u=tid; u<TP*8; u+=128){
    int tt = u>>3, gg = u&7;
    y[(rbase+tt)*DI + d0 + gg] = z_s[u];
  }
}

// ---------- masked mean pool + 2-layer classifier. grid = 8, block = 128.
__global__ void k_head(const float* __restrict__ hln, const int* __restrict__ lengths,
                       const float* __restrict__ w1, const float* __restrict__ b1,
                       const float* __restrict__ w2, const float* __restrict__ b2,
                       float* __restrict__ out){
  __shared__ float pooled[DM];
  __shared__ float cbuf[64];
  int b = blockIdx.x, tid = threadIdx.x;
  int tl = lengths[b] >> 1; if(tl < 1) tl = 1;
  float s = 0.f;
  const float* p = hln + (size_t)b*TP*DM + tid;
  for(int t=0;t<tl;t++) s += p[(size_t)t*DM];
  pooled[tid] = s / (float)tl;
  __syncthreads();
  if(tid < 64){
    float a = b1[tid];
    const float* wp = w1 + tid*DM;
    for(int k=0;k<DM;k++) a = fmaf(pooled[k], wp[k], a);
    cbuf[tid] = fsilu(a);
  }
  __syncthreads();
  if(tid < 35){
    float a = b2[tid];
    const float* wp = w2 + tid*64;
    for(int k=0;k<64;k++) a = fmaf(cbuf[k], wp[k], a);
    out[b*35+tid] = a;
  }
}

extern "C" void kernel_launch(void* const* d_in, const int* in_sizes, int n_in,
                              void* d_out, int out_size, void* d_ws, size_t ws_size,
                              hipStream_t stream){
  (void)in_sizes; (void)n_in; (void)out_size; (void)ws_size;
  const float* x        = (const float*)d_in[0];
  const int*   lengths  = (const int*)  d_in[1];
  const float* conv_w1  = (const float*)d_in[2];  const float* conv_b1 = (const float*)d_in[3];
  const float* bn1_s    = (const float*)d_in[4];  const float* bn1_b   = (const float*)d_in[5];
  const float* conv_w2  = (const float*)d_in[6];  const float* conv_b2 = (const float*)d_in[7];
  const float* bn2_s    = (const float*)d_in[8];  const float* bn2_b   = (const float*)d_in[9];
  const float* conv_w3  = (const float*)d_in[10]; const float* conv_b3 = (const float*)d_in[11];
  const float* bn3_s    = (const float*)d_in[12]; const float* bn3_b   = (const float*)d_in[13];
  const float* conv_w4  = (const float*)d_in[14]; const float* conv_b4 = (const float*)d_in[15];
  const float* bn4_s    = (const float*)d_in[16]; const float* bn4_b   = (const float*)d_in[17];
  const float* proj_w   = (const float*)d_in[18]; const float* proj_b  = (const float*)d_in[19];
  const float* proj_ln_s= (const float*)d_in[20]; const float* proj_ln_b=(const float*)d_in[21];
  const float* blk_ln_s = (const float*)d_in[22]; const float* blk_ln_b =(const float*)d_in[23];
  const float* in_w     = (const float*)d_in[24];
  const float* cw       = (const float*)d_in[25]; const float* cbv     = (const float*)d_in[26];
  const float* xp_w     = (const float*)d_in[27];
  const float* dt_w     = (const float*)d_in[28]; const float* dt_b    = (const float*)d_in[29];
  const float* A_log    = (const float*)d_in[30]; const float* Dp      = (const float*)d_in[31];
  const float* out_w    = (const float*)d_in[32];
  const float* pre_ln_s = (const float*)d_in[33]; const float* pre_ln_b= (const float*)d_in[34];
  const float* cls_w1   = (const float*)d_in[35]; const float* cls_b1  = (const float*)d_in[36];
  const float* cls_w2   = (const float*)d_in[37]; const float* cls_b2  = (const float*)d_in[38];

  float* ws   = (float*)d_ws;
  float* R0   = ws;                  // 16,777,216 floats (conv ping)
  float* R1   = R0 + 16777216;       // 16,777,216 floats (conv pong)
  float* xT   = R1 + 16777216;       // 524,288
  float* hbuf = xT + 524288;         // 262,144
  float* lnb  = hbuf + 262144;       // 262,144
  float* xzb  = lnb + 262144;        // 1,048,576
  float* xcb  = xzb + 1048576;       // 524,288
  float* dbcb = xcb + 524288;        // 81,920
  float* dtbb = dbcb + 81920;        // 524,288
  float* yb   = dtbb + 524288;       // 524,288
  // total ~37.3M floats = ~143 MB

  // ---- frontend
  k_transpose_x<<<2048, 256, 0, stream>>>(x, xT);
  k_conv3x3<<<8*16*128, 128, 0, stream>>>(xT, conv_w1, conv_b1, bn1_s, bn1_b, R0, 1, 32, 128, 512);
  k_conv3x3<<<8*16*128, 128, 0, stream>>>(R0, conv_w2, conv_b2, bn2_s, bn2_b, R1, 32, 32, 128, 512);
  k_pool2x2<<<(8*32*64*256)/256, 256, 0, stream>>>(R1, R0, 32, 128, 512);
  k_conv3x3<<<8*32*64, 64, 0, stream>>>(R0, conv_w3, conv_b3, bn3_s, bn3_b, R1, 32, 64, 64, 256);
  k_conv3x3<<<8*32*64, 64, 0, stream>>>(R1, conv_w4, conv_b4, bn4_s, bn4_b, R0, 64, 64, 64, 256);
  k_pool2x1t<<<(8*256*2048)/256, 256, 0, stream>>>(R0, R1);

  // ---- projection: [2048,2048] @ [128,2048]^T + b -> hbuf, then LN+SiLU
  {
    dim3 g(2, 32);
    k_gemm<0,0><<<g, 256, 0, stream>>>(R1, 2048, proj_w, proj_b, hbuf, 2048, 128, 2048);
  }
  k_ln<1><<<2048, 64, 0, stream>>>(hbuf, proj_ln_s, proj_ln_b, hbuf);

  // ---- mamba layers
  for(int i=0;i<NL;i++){
    k_ln<0><<<2048, 64, 0, stream>>>(hbuf, blk_ln_s + i*DM, blk_ln_b + i*DM, lnb);
    { dim3 g(8, 32);  // xz = ln @ in_w^T : [2048,512]
      k_gemm<0,0><<<g, 256, 0, stream>>>(lnb, DM, in_w + (size_t)i*512*DM, nullptr, xzb, 2048, 512, DM); }
    k_dwconv<<<2048, 256, 0, stream>>>(xzb, cw + (size_t)i*DI*4, cbv + i*DI, xcb);
    { dim3 g(1, 32);  // dbc = xc @ xp_w^T : [2048,40]
      k_gemm<0,0><<<g, 256, 0, stream>>>(xcb, DI, xp_w + (size_t)i*40*DI, nullptr, dbcb, 2048, 40, DI); }
    { dim3 g(4, 32);  // dt = softplus(dbc[:,:8] @ dt_w^T + dt_b) : [2048,256]
      k_gemm<2,0><<<g, 256, 0, stream>>>(dbcb, 40, dt_w + (size_t)i*DI*DTR, dt_b + i*DI, dtbb, 2048, 256, 8); }
    k_scan<<<256, 128, 0, stream>>>(dtbb, xcb, xzb, dbcb, A_log + (size_t)i*DI*DS, Dp + i*DI, yb);
    { dim3 g(2, 32);  // hbuf += y @ out_w^T : [2048,128]
      k_gemm<0,1><<<g, 256, 0, stream>>>(yb, DI, out_w + (size_t)i*DM*DI, nullptr, hbuf, 2048, 128, DI); }
  }

  // ---- head
  k_ln<0><<<2048, 64, 0, stream>>>(hbuf, pre_ln_s, pre_ln_b, lnb);
  k_head<<<8, 128, 0, stream>>>(lnb, lengths, cls_w1, cls_b1, cls_w2, cls_b2, (float*)d_out);
}

// Round 2
// 1997.619 us; speedup vs baseline: 2.0858x; 2.0858x over previous
//
#include <hip/hip_runtime.h>
#include <math.h>

#define B_ 8
#define T_ 512
#define FEAT_ 128
#define TP 256          // T' after frontend
#define DM 128          // d_model
#define DI 256          // d_inner
#define DS 16           // d_state
#define DTR 8
#define NL 10

__device__ __forceinline__ float fsilu(float x){ return x / (1.f + __expf(-x)); }
__device__ __forceinline__ float fsoftplus(float x){ return (x > 20.f) ? x : log1pf(__expf(x)); }

// ---------- transpose x [8,512,128] -> xT [8,128,512]
__global__ void k_transpose_x(const float* __restrict__ x, float* __restrict__ xT){
  int idx = blockIdx.x*256 + threadIdx.x;
  if(idx >= B_*FEAT_*T_) return;
  int t = idx % T_; int f = (idx/T_) % FEAT_; int b = idx/(T_*FEAT_);
  xT[idx] = x[((size_t)b*T_ + t)*FEAT_ + f];
}

// ---------- weight transpose [CO,CIN,9] -> [CIN,CO,9]
__global__ void k_wt(const float* __restrict__ w, float* __restrict__ wt, int CO, int CIN){
  int idx = blockIdx.x*256 + threadIdx.x;
  if(idx >= CO*CIN*9) return;
  int k = idx % 9; int ci = (idx/9) % CIN; int co = idx/(9*CIN);
  wt[((size_t)ci*CO + co)*9 + k] = w[idx];
}

// ---------- tiled direct 3x3 SAME conv + folded BN + SiLU.
// block = 256 thr = 4 waves; tile 16x16 outputs; wave w computes CPW channels
// [w*CPW, (w+1)*CPW). Input staged CIG channels at a time into LDS.
// Weights pre-transposed to [ci][co][9]; index is wave-uniform -> s_load.
template<int CIN, int CO, int CPW, int CIG>
__global__ __launch_bounds__(256) void k_conv_t(const float* __restrict__ in,
     const float* __restrict__ wt, const float* __restrict__ cb,
     const float* __restrict__ bs, const float* __restrict__ bb,
     float* __restrict__ out, int H, int W){
  __shared__ __align__(16) float tile[CIG][18][20];
  int tid = threadIdx.x;
  int lane = tid & 63;
  int wav = __builtin_amdgcn_readfirstlane(tid >> 6);
  int wpr = W >> 4;
  int tj = blockIdx.x % wpr;
  int ti = (blockIdx.x / wpr) % (H >> 4);
  int b  = blockIdx.x / (wpr * (H >> 4));
  int i0 = ti*16, j0 = tj*16;
  int r = lane >> 2, cg = lane & 3;
  float acc[CPW][4] = {};
  for(int cig = 0; cig < CIN; cig += CIG){
    __syncthreads();
    for(int u = tid; u < CIG*18*18; u += 256){
      int ci = u / 324; int rem = u % 324; int rr = rem / 18; int cc = rem % 18;
      int gi = i0 - 1 + rr, gj = j0 - 1 + cc;
      float v = 0.f;
      if(gi >= 0 && gi < H && gj >= 0 && gj < W)
        v = in[((size_t)(b*CIN + cig + ci)*H + gi)*W + gj];
      tile[ci][rr][cc] = v;
    }
    __syncthreads();
    for(int ci = 0; ci < CIG; ci++){
      float v[3][6];
      #pragma unroll
      for(int kh=0;kh<3;kh++){
        float4 t4 = *(const float4*)&tile[ci][r+kh][cg*4];
        v[kh][0]=t4.x; v[kh][1]=t4.y; v[kh][2]=t4.z; v[kh][3]=t4.w;
        v[kh][4]=tile[ci][r+kh][cg*4+4];
        v[kh][5]=tile[ci][r+kh][cg*4+5];
      }
      const float* wp = wt + ((size_t)(cig+ci)*CO + wav*CPW)*9;
      #pragma unroll
      for(int co=0; co<CPW; co++){
        #pragma unroll
        for(int kh=0;kh<3;kh++){
          #pragma unroll
          for(int kw=0;kw<3;kw++){
            float wv = wp[co*9 + kh*3 + kw];
            #pragma unroll
            for(int u2=0;u2<4;u2++)
              acc[co][u2] = fmaf(wv, v[kh][kw+u2], acc[co][u2]);
          }
        }
      }
    }
  }
  int i = i0 + r;
  #pragma unroll
  for(int co=0; co<CPW; co++){
    int c = wav*CPW + co;
    float s = bs[c], bias = cb[c]*s + bb[c];
    float4 o;
    o.x = fsilu(acc[co][0]*s + bias);
    o.y = fsilu(acc[co][1]*s + bias);
    o.z = fsilu(acc[co][2]*s + bias);
    o.w = fsilu(acc[co][3]*s + bias);
    *(float4*)&out[((size_t)(b*CO + c)*H + i)*W + j0 + cg*4] = o;
  }
}

// ---------- 2x2 max pool stride 2
__global__ void k_pool2x2(const float* __restrict__ in, float* __restrict__ out,
                          int C, int Hi, int Wi){
  int Ho = Hi>>1, Wo = Wi>>1;
  int total = B_*C*Ho*Wo;
  int idx = blockIdx.x*256 + threadIdx.x;
  if(idx >= total) return;
  int j = idx % Wo; int i = (idx/Wo)%Ho; int c = (idx/(Wo*Ho))%C; int b = idx/(Wo*Ho*C);
  const float* p = in + (((size_t)(b*C+c)*Hi + 2*i)*Wi + 2*j);
  out[idx] = fmaxf(fmaxf(p[0], p[1]), fmaxf(p[Wi], p[Wi+1]));
}

// ---------- (2,1) max pool + transpose to [b*256+t][c*32+hh]  (proj GEMM A-matrix)
__global__ void k_pool2x1t(const float* __restrict__ in, float* __restrict__ out){
  // in: [8,64,64,256]
  int idx = blockIdx.x*256 + threadIdx.x; // 8*256*2048
  if(idx >= B_*TP*2048) return;
  int f = idx & 2047; int t = (idx>>11) & (TP-1); int b = idx >> 19;
  int c = f >> 5, hh = f & 31;
  const float* p = in + (((size_t)(b*64+c)*64 + 2*hh)*256 + t);
  out[idx] = fmaxf(p[0], p[256]);
}

// ---------- generic fp32 GEMM: C[M,N] = act(A[M,K(lda)] @ W[N,K]^T + bias) (+residual)
// block tile 64x64, BK=16, 256 threads, 4x4 per thread.
template<int ACT, int RES>  // ACT: 0 none, 1 silu, 2 softplus
__global__ __launch_bounds__(256) void k_gemm(const float* __restrict__ A, int lda,
              const float* __restrict__ W, const float* __restrict__ bias,
              float* __restrict__ C, int M, int N, int K){
  __shared__ __align__(16) float As[16][64];
  __shared__ __align__(16) float Ws[16][64];
  int tid = threadIdx.x;
  int n0 = blockIdx.x*64, m0 = blockIdx.y*64;
  int ra = tid>>2, ca = (tid&3)*4;
  int tx = tid & 15, ty = tid >> 4;
  float acc[4][4] = {};
  for(int k0=0; k0<K; k0+=16){
    int k = k0 + ca;
    {
      int m = m0 + ra;
      if(m < M && (k+3) < K){
        float4 v = *(const float4*)(A + (size_t)m*lda + k);
        As[ca+0][ra]=v.x; As[ca+1][ra]=v.y; As[ca+2][ra]=v.z; As[ca+3][ra]=v.w;
      } else {
        #pragma unroll
        for(int c=0;c<4;c++) As[ca+c][ra] = (m<M && (k+c)<K) ? A[(size_t)m*lda + k + c] : 0.f;
      }
      int n = n0 + ra;
      if(n < N && (k+3) < K){
        float4 v = *(const float4*)(W + (size_t)n*K + k);
        Ws[ca+0][ra]=v.x; Ws[ca+1][ra]=v.y; Ws[ca+2][ra]=v.z; Ws[ca+3][ra]=v.w;
      } else {
        #pragma unroll
        for(int c=0;c<4;c++) Ws[ca+c][ra] = (n<N && (k+c)<K) ? W[(size_t)n*K + k + c] : 0.f;
      }
    }
    __syncthreads();
    #pragma unroll
    for(int kk=0; kk<16; kk++){
      float4 a4 = *(const float4*)&As[kk][ty*4];
      float4 w4 = *(const float4*)&Ws[kk][tx*4];
      float av[4] = {a4.x,a4.y,a4.z,a4.w};
      float wv[4] = {w4.x,w4.y,w4.z,w4.w};
      #pragma unroll
      for(int iu=0; iu<4; iu++)
        #pragma unroll
        for(int ju=0; ju<4; ju++)
          acc[iu][ju] = fmaf(av[iu], wv[ju], acc[iu][ju]);
    }
    __syncthreads();
  }
  #pragma unroll
  for(int iu=0; iu<4; iu++){
    int m = m0 + ty*4 + iu;
    if(m >= M) continue;
    #pragma unroll
    for(int ju=0; ju<4; ju++){
      int n = n0 + tx*4 + ju;
      if(n >= N) continue;
      float v = acc[iu][ju];
      if(bias) v += bias[n];
      if(ACT==1) v = fsilu(v);
      else if(ACT==2) v = fsoftplus(v);
      size_t o = (size_t)m*N + n;
      if(RES) v += C[o];
      C[o] = v;
    }
  }
}

// ---------- LayerNorm over last dim (128), optional SiLU. 1 wave per row.
template<int SILU>
__global__ void k_ln(const float* __restrict__ in, const float* __restrict__ g,
                     const float* __restrict__ b, float* __restrict__ out){
  int row = blockIdx.x;
  int t = threadIdx.x; // 64
  const float* p = in + (size_t)row*DM;
  float v0 = p[t], v1 = p[t+64];
  float s = v0 + v1;
  #pragma unroll
  for(int m=32;m>=1;m>>=1) s += __shfl_xor(s, m);
  float mean = s * (1.f/128.f);
  float e0 = v0-mean, e1 = v1-mean;
  float q = e0*e0 + e1*e1;
  #pragma unroll
  for(int m=32;m>=1;m>>=1) q += __shfl_xor(q, m);
  float inv = rsqrtf(q*(1.f/128.f) + 1e-5f);
  float o0 = e0*inv*g[t] + b[t];
  float o1 = e1*inv*g[t+64] + b[t+64];
  if(SILU){ o0 = fsilu(o0); o1 = fsilu(o1); }
  float* po = out + (size_t)row*DM;
  po[t] = o0; po[t+64] = o1;
}

// ---------- causal depthwise conv1d (width 4, left-pad 3) + SiLU
__global__ void k_dwconv(const float* __restrict__ xz, const float* __restrict__ cw,
                         const float* __restrict__ cb, float* __restrict__ xc){
  int idx = blockIdx.x*256 + threadIdx.x;
  if(idx >= B_*TP*DI) return;
  int d = idx & (DI-1);
  int t = (idx >> 8) & (TP-1);
  int b = idx >> 16;
  const float* base = xz + ((size_t)(b*TP))*512 + d;
  float acc = cb[d];
  #pragma unroll
  for(int k=0;k<4;k++){
    int tt = t - 3 + k;
    if(tt >= 0) acc = fmaf(cw[d*4+k], base[(size_t)tt*512], acc);
  }
  xc[idx] = fsilu(acc);
}

// ---------- selective scan + D skip + z gate.
// grid = 8(b) * 32(d-blocks of 8), block = 128 (8 d-groups x 16 states).
__global__ __launch_bounds__(128) void k_scan(const float* __restrict__ dtb,
      const float* __restrict__ xc, const float* __restrict__ xz,
      const float* __restrict__ dbc, const float* __restrict__ A_log,
      const float* __restrict__ Dp, float* __restrict__ y){
  __shared__ float dt_s[TP*8], xc_s[TP*8], z_s[TP*8];
  __shared__ float Bs[TP*16], Cs[TP*16];
  int tid = threadIdx.x;
  int dblk = blockIdx.x & 31;
  int b = blockIdx.x >> 5;
  int d0 = dblk*8;
  size_t rbase = (size_t)b*TP;
  for(int u=tid; u<TP*8; u+=128){
    int tt = u>>3, gg = u&7;
    size_t r = rbase + tt;
    dt_s[u] = dtb[r*DI + d0 + gg];
    xc_s[u] = xc [r*DI + d0 + gg];
    z_s[u]  = xz [r*512 + DI + d0 + gg];
  }
  for(int u=tid; u<TP*16; u+=128){
    int tt = u>>4, nn = u&15;
    size_t r = rbase + tt;
    Bs[u] = dbc[r*40 + 8  + nn];
    Cs[u] = dbc[r*40 + 24 + nn];
  }
  __syncthreads();
  int g = tid >> 4, n = tid & 15;
  int d = d0 + g;
  float An = -__expf(A_log[d*DS + n]);
  float Dpd = Dp[d];
  float h = 0.f;
  for(int t=0;t<TP;t++){
    float dtv = dt_s[t*8+g];
    float xcv = xc_s[t*8+g];
    float Bv  = Bs[t*16+n];
    float Cv  = Cs[t*16+n];
    float e = __expf(dtv*An);
    h = fmaf(e, h, dtv*xcv*Bv);
    float p = h*Cv;
    p += __shfl_xor(p,1); p += __shfl_xor(p,2);
    p += __shfl_xor(p,4); p += __shfl_xor(p,8);
    if(n==0){
      float zv = z_s[t*8+g];
      z_s[t*8+g] = (p + Dpd*xcv) * fsilu(zv);
    }
  }
  __syncthreads();
  for(int u=tid; u<TP*8; u+=128){
    int tt = u>>3, gg = u&7;
    y[(rbase+tt)*DI + d0 + gg] = z_s[u];
  }
}

// ---------- masked mean pool + 2-layer classifier. grid = 8, block = 128.
__global__ void k_head(const float* __restrict__ hln, const int* __restrict__ lengths,
                       const float* __restrict__ w1, const float* __restrict__ b1,
                       const float* __restrict__ w2, const float* __restrict__ b2,
                       float* __restrict__ out){
  __shared__ float pooled[DM];
  __shared__ float cbuf[64];
  int b = blockIdx.x, tid = threadIdx.x;
  int tl = lengths[b] >> 1; if(tl < 1) tl = 1;
  float s = 0.f;
  const float* p = hln + (size_t)b*TP*DM + tid;
  for(int t=0;t<tl;t++) s += p[(size_t)t*DM];
  pooled[tid] = s / (float)tl;
  __syncthreads();
  if(tid < 64){
    float a = b1[tid];
    const float* wp = w1 + tid*DM;
    for(int k=0;k<DM;k++) a = fmaf(pooled[k], wp[k], a);
    cbuf[tid] = fsilu(a);
  }
  __syncthreads();
  if(tid < 35){
    float a = b2[tid];
    const float* wp = w2 + tid*64;
    for(int k=0;k<64;k++) a = fmaf(cbuf[k], wp[k], a);
    out[b*35+tid] = a;
  }
}

extern "C" void kernel_launch(void* const* d_in, const int* in_sizes, int n_in,
                              void* d_out, int out_size, void* d_ws, size_t ws_size,
                              hipStream_t stream){
  (void)in_sizes; (void)n_in; (void)out_size; (void)ws_size;
  const float* x        = (const float*)d_in[0];
  const int*   lengths  = (const int*)  d_in[1];
  const float* conv_w1  = (const float*)d_in[2];  const float* conv_b1 = (const float*)d_in[3];
  const float* bn1_s    = (const float*)d_in[4];  const float* bn1_b   = (const float*)d_in[5];
  const float* conv_w2  = (const float*)d_in[6];  const float* conv_b2 = (const float*)d_in[7];
  const float* bn2_s    = (const float*)d_in[8];  const float* bn2_b   = (const float*)d_in[9];
  const float* conv_w3  = (const float*)d_in[10]; const float* conv_b3 = (const float*)d_in[11];
  const float* bn3_s    = (const float*)d_in[12]; const float* bn3_b   = (const float*)d_in[13];
  const float* conv_w4  = (const float*)d_in[14]; const float* conv_b4 = (const float*)d_in[15];
  const float* bn4_s    = (const float*)d_in[16]; const float* bn4_b   = (const float*)d_in[17];
  const float* proj_w   = (const float*)d_in[18]; const float* proj_b  = (const float*)d_in[19];
  const float* proj_ln_s= (const float*)d_in[20]; const float* proj_ln_b=(const float*)d_in[21];
  const float* blk_ln_s = (const float*)d_in[22]; const float* blk_ln_b =(const float*)d_in[23];
  const float* in_w     = (const float*)d_in[24];
  const float* cw       = (const float*)d_in[25]; const float* cbv     = (const float*)d_in[26];
  const float* xp_w     = (const float*)d_in[27];
  const float* dt_w     = (const float*)d_in[28]; const float* dt_b    = (const float*)d_in[29];
  const float* A_log    = (const float*)d_in[30]; const float* Dp      = (const float*)d_in[31];
  const float* out_w    = (const float*)d_in[32];
  const float* pre_ln_s = (const float*)d_in[33]; const float* pre_ln_b= (const float*)d_in[34];
  const float* cls_w1   = (const float*)d_in[35]; const float* cls_b1  = (const float*)d_in[36];
  const float* cls_w2   = (const float*)d_in[37]; const float* cls_b2  = (const float*)d_in[38];

  float* ws   = (float*)d_ws;
  float* R0   = ws;                  // 16,777,216 floats (conv ping)
  float* R1   = R0 + 16777216;       // 16,777,216 floats (conv pong)
  float* xT   = R1 + 16777216;       // 524,288
  float* hbuf = xT + 524288;         // 262,144
  float* lnb  = hbuf + 262144;       // 262,144
  float* xzb  = lnb + 262144;        // 1,048,576
  float* xcb  = xzb + 1048576;       // 524,288
  float* dbcb = xcb + 524288;        // 81,920
  float* dtbb = dbcb + 81920;        // 524,288
  float* yb   = dtbb + 524288;       // 524,288
  float* wt1  = yb + 524288;         // 288
  float* wt2  = wt1 + 288;           // 9,216
  float* wt3  = wt2 + 9216;          // 18,432
  float* wt4  = wt3 + 18432;         // 36,864

  // ---- weight transposes (tiny)
  k_wt<<<(32*1*9 + 255)/256, 256, 0, stream>>>(conv_w1, wt1, 32, 1);
  k_wt<<<(32*32*9 + 255)/256, 256, 0, stream>>>(conv_w2, wt2, 32, 32);
  k_wt<<<(64*32*9 + 255)/256, 256, 0, stream>>>(conv_w3, wt3, 64, 32);
  k_wt<<<(64*64*9 + 255)/256, 256, 0, stream>>>(conv_w4, wt4, 64, 64);

  // ---- frontend
  k_transpose_x<<<2048, 256, 0, stream>>>(x, xT);
  k_conv_t<1,32,8,1><<<8*8*32, 256, 0, stream>>>(xT, wt1, conv_b1, bn1_s, bn1_b, R0, 128, 512);
  k_conv_t<32,32,8,8><<<8*8*32, 256, 0, stream>>>(R0, wt2, conv_b2, bn2_s, bn2_b, R1, 128, 512);
  k_pool2x2<<<(8*32*64*256)/256, 256, 0, stream>>>(R1, R0, 32, 128, 512);
  k_conv_t<32,64,16,8><<<8*4*16, 256, 0, stream>>>(R0, wt3, conv_b3, bn3_s, bn3_b, R1, 64, 256);
  k_conv_t<64,64,16,8><<<8*4*16, 256, 0, stream>>>(R1, wt4, conv_b4, bn4_s, bn4_b, R0, 64, 256);
  k_pool2x1t<<<(8*256*2048)/256, 256, 0, stream>>>(R0, R1);

  // ---- projection: [2048,2048] @ [128,2048]^T + b -> hbuf, then LN+SiLU
  {
    dim3 g(2, 32);
    k_gemm<0,0><<<g, 256, 0, stream>>>(R1, 2048, proj_w, proj_b, hbuf, 2048, 128, 2048);
  }
  k_ln<1><<<2048, 64, 0, stream>>>(hbuf, proj_ln_s, proj_ln_b, hbuf);

  // ---- mamba layers
  for(int i=0;i<NL;i++){
    k_ln<0><<<2048, 64, 0, stream>>>(hbuf, blk_ln_s + i*DM, blk_ln_b + i*DM, lnb);
    { dim3 g(8, 32);  // xz = ln @ in_w^T : [2048,512]
      k_gemm<0,0><<<g, 256, 0, stream>>>(lnb, DM, in_w + (size_t)i*512*DM, nullptr, xzb, 2048, 512, DM); }
    k_dwconv<<<2048, 256, 0, stream>>>(xzb, cw + (size_t)i*DI*4, cbv + i*DI, xcb);
    { dim3 g(1, 32);  // dbc = xc @ xp_w^T : [2048,40]
      k_gemm<0,0><<<g, 256, 0, stream>>>(xcb, DI, xp_w + (size_t)i*40*DI, nullptr, dbcb, 2048, 40, DI); }
    { dim3 g(4, 32);  // dt = softplus(dbc[:,:8] @ dt_w^T + dt_b) : [2048,256]
      k_gemm<2,0><<<g, 256, 0, stream>>>(dbcb, 40, dt_w + (size_t)i*DI*DTR, dt_b + i*DI, dtbb, 2048, 256, 8); }
    k_scan<<<256, 128, 0, stream>>>(dtbb, xcb, xzb, dbcb, A_log + (size_t)i*DI*DS, Dp + i*DI, yb);
    { dim3 g(2, 32);  // hbuf += y @ out_w^T : [2048,128]
      k_gemm<0,1><<<g, 256, 0, stream>>>(yb, DI, out_w + (size_t)i*DM*DI, nullptr, hbuf, 2048, 128, DI); }
  }

  // ---- head
  k_ln<0><<<2048, 64, 0, stream>>>(hbuf, pre_ln_s, pre_ln_b, lnb);
  k_head<<<8, 128, 0, stream>>>(lnb, lengths, cls_w1, cls_b1, cls_w2, cls_b2, (float*)d_out);
}

// Round 3
// 1742.232 us; speedup vs baseline: 2.3915x; 1.1466x over previous
//
#include <hip/hip_runtime.h>
#include <math.h>

#define B_ 8
#define T_ 512
#define FEAT_ 128
#define TP 256          // T' after frontend
#define DM 128          // d_model
#define DI 256          // d_inner
#define DS 16           // d_state
#define DTR 8
#define NL 10

__device__ __forceinline__ float fsilu(float x){ return x / (1.f + __expf(-x)); }
__device__ __forceinline__ float fsoftplus(float x){ return (x > 20.f) ? x : log1pf(__expf(x)); }

// ---------- transpose x [8,512,128] -> xT [8,128,512]
__global__ void k_transpose_x(const float* __restrict__ x, float* __restrict__ xT){
  int idx = blockIdx.x*256 + threadIdx.x;
  if(idx >= B_*FEAT_*T_) return;
  int t = idx % T_; int f = (idx/T_) % FEAT_; int b = idx/(T_*FEAT_);
  xT[idx] = x[((size_t)b*T_ + t)*FEAT_ + f];
}

// ---------- weight transpose [CO,CIN,9] -> [CIN,CO,9]
__global__ void k_wt(const float* __restrict__ w, float* __restrict__ wt, int CO, int CIN){
  int idx = blockIdx.x*256 + threadIdx.x;
  if(idx >= CO*CIN*9) return;
  int k = idx % 9; int ci = (idx/9) % CIN; int co = idx/(9*CIN);
  wt[((size_t)ci*CO + co)*9 + k] = w[idx];
}

// ---------- tiled direct 3x3 SAME conv + folded BN + SiLU. v2:
// stride-19 LDS rows (bank-conflict-free scalar reads), CO-split via COG.
// block = 256 thr = 4 waves; tile 16x16; wave computes CPW channels at
// coBase = cog*(CO/COG) + wav*CPW. Weights [ci][co][9] wave-uniform -> s_load.
template<int CIN, int CO, int CPW, int CIG, int COG>
__global__ __launch_bounds__(256) void k_conv_t2(const float* __restrict__ in,
     const float* __restrict__ wt, const float* __restrict__ cb,
     const float* __restrict__ bs, const float* __restrict__ bb,
     float* __restrict__ out, int H, int W){
  __shared__ float tile[CIG*342];   // [CIG][18][19]
  int tid = threadIdx.x;
  int lane = tid & 63;
  int wav = __builtin_amdgcn_readfirstlane(tid >> 6);
  int wpr = W >> 4, hpr = H >> 4;
  int idx = blockIdx.x;
  int cog = idx % COG; idx /= COG;
  int tj = idx % wpr; idx /= wpr;
  int ti = idx % hpr; int b = idx / hpr;
  int i0 = ti*16, j0 = tj*16;
  int r = lane >> 2, cg = lane & 3;
  int coBase = cog*(CO/COG) + wav*CPW;
  float acc[CPW][4] = {};
  for(int cig = 0; cig < CIN; cig += CIG){
    __syncthreads();
    for(int u = tid; u < CIG*324; u += 256){
      int ci = u / 324; int rem = u % 324; int rr = rem / 18; int cc = rem % 18;
      int gi = i0 - 1 + rr, gj = j0 - 1 + cc;
      float v = 0.f;
      if(gi >= 0 && gi < H && gj >= 0 && gj < W)
        v = in[((size_t)(b*CIN + cig + ci)*H + gi)*W + gj];
      tile[ci*342 + rr*19 + cc] = v;
    }
    __syncthreads();
    for(int ci = 0; ci < CIG; ci++){
      float v[3][6];
      #pragma unroll
      for(int kh=0;kh<3;kh++){
        #pragma unroll
        for(int c2=0;c2<6;c2++)
          v[kh][c2] = tile[ci*342 + (r+kh)*19 + cg*4 + c2];
      }
      const float* wp = wt + ((size_t)(cig+ci)*CO + coBase)*9;
      #pragma unroll
      for(int co=0; co<CPW; co++){
        #pragma unroll
        for(int kh=0;kh<3;kh++){
          #pragma unroll
          for(int kw=0;kw<3;kw++){
            float wv = wp[co*9 + kh*3 + kw];
            #pragma unroll
            for(int u2=0;u2<4;u2++)
              acc[co][u2] = fmaf(wv, v[kh][kw+u2], acc[co][u2]);
          }
        }
      }
    }
  }
  int i = i0 + r;
  #pragma unroll
  for(int co=0; co<CPW; co++){
    int c = coBase + co;
    float s = bs[c], bias = cb[c]*s + bb[c];
    float4 o;
    o.x = fsilu(acc[co][0]*s + bias);
    o.y = fsilu(acc[co][1]*s + bias);
    o.z = fsilu(acc[co][2]*s + bias);
    o.w = fsilu(acc[co][3]*s + bias);
    *(float4*)&out[((size_t)(b*CO + c)*H + i)*W + j0 + cg*4] = o;
  }
}

// ---------- 2x2 max pool stride 2
__global__ void k_pool2x2(const float* __restrict__ in, float* __restrict__ out,
                          int C, int Hi, int Wi){
  int Ho = Hi>>1, Wo = Wi>>1;
  int total = B_*C*Ho*Wo;
  int idx = blockIdx.x*256 + threadIdx.x;
  if(idx >= total) return;
  int j = idx % Wo; int i = (idx/Wo)%Ho; int c = (idx/(Wo*Ho))%C; int b = idx/(Wo*Ho*C);
  const float* p = in + (((size_t)(b*C+c)*Hi + 2*i)*Wi + 2*j);
  out[idx] = fmaxf(fmaxf(p[0], p[1]), fmaxf(p[Wi], p[Wi+1]));
}

// ---------- (2,1) max pool + transpose to [b*256+t][c*32+hh]
__global__ void k_pool2x1t(const float* __restrict__ in, float* __restrict__ out){
  int idx = blockIdx.x*256 + threadIdx.x; // 8*256*2048
  if(idx >= B_*TP*2048) return;
  int f = idx & 2047; int t = (idx>>11) & (TP-1); int b = idx >> 19;
  int c = f >> 5, hh = f & 31;
  const float* p = in + (((size_t)(b*64+c)*64 + 2*hh)*256 + t);
  out[idx] = fmaxf(p[0], p[256]);
}

// ---------- generic fp32 GEMM: C[M,N] = act(A[M,K(lda)] @ W[N,K]^T + bias) (+residual)
template<int ACT, int RES>
__global__ __launch_bounds__(256) void k_gemm(const float* __restrict__ A, int lda,
              const float* __restrict__ W, const float* __restrict__ bias,
              float* __restrict__ C, int M, int N, int K){
  __shared__ __align__(16) float As[16][64];
  __shared__ __align__(16) float Ws[16][64];
  int tid = threadIdx.x;
  int n0 = blockIdx.x*64, m0 = blockIdx.y*64;
  int ra = tid>>2, ca = (tid&3)*4;
  int tx = tid & 15, ty = tid >> 4;
  float acc[4][4] = {};
  for(int k0=0; k0<K; k0+=16){
    int k = k0 + ca;
    {
      int m = m0 + ra;
      if(m < M && (k+3) < K){
        float4 v = *(const float4*)(A + (size_t)m*lda + k);
        As[ca+0][ra]=v.x; As[ca+1][ra]=v.y; As[ca+2][ra]=v.z; As[ca+3][ra]=v.w;
      } else {
        #pragma unroll
        for(int c=0;c<4;c++) As[ca+c][ra] = (m<M && (k+c)<K) ? A[(size_t)m*lda + k + c] : 0.f;
      }
      int n = n0 + ra;
      if(n < N && (k+3) < K){
        float4 v = *(const float4*)(W + (size_t)n*K + k);
        Ws[ca+0][ra]=v.x; Ws[ca+1][ra]=v.y; Ws[ca+2][ra]=v.z; Ws[ca+3][ra]=v.w;
      } else {
        #pragma unroll
        for(int c=0;c<4;c++) Ws[ca+c][ra] = (n<N && (k+c)<K) ? W[(size_t)n*K + k + c] : 0.f;
      }
    }
    __syncthreads();
    #pragma unroll
    for(int kk=0; kk<16; kk++){
      float4 a4 = *(const float4*)&As[kk][ty*4];
      float4 w4 = *(const float4*)&Ws[kk][tx*4];
      float av[4] = {a4.x,a4.y,a4.z,a4.w};
      float wv[4] = {w4.x,w4.y,w4.z,w4.w};
      #pragma unroll
      for(int iu=0; iu<4; iu++)
        #pragma unroll
        for(int ju=0; ju<4; ju++)
          acc[iu][ju] = fmaf(av[iu], wv[ju], acc[iu][ju]);
    }
    __syncthreads();
  }
  #pragma unroll
  for(int iu=0; iu<4; iu++){
    int m = m0 + ty*4 + iu;
    if(m >= M) continue;
    #pragma unroll
    for(int ju=0; ju<4; ju++){
      int n = n0 + tx*4 + ju;
      if(n >= N) continue;
      float v = acc[iu][ju];
      if(bias) v += bias[n];
      if(ACT==1) v = fsilu(v);
      else if(ACT==2) v = fsoftplus(v);
      size_t o = (size_t)m*N + n;
      if(RES) v += C[o];
      C[o] = v;
    }
  }
}

// ---------- LayerNorm over last dim (128), optional SiLU. 1 wave per row.
template<int SILU>
__global__ void k_ln(const float* __restrict__ in, const float* __restrict__ g,
                     const float* __restrict__ b, float* __restrict__ out){
  int row = blockIdx.x;
  int t = threadIdx.x; // 64
  const float* p = in + (size_t)row*DM;
  float v0 = p[t], v1 = p[t+64];
  float s = v0 + v1;
  #pragma unroll
  for(int m=32;m>=1;m>>=1) s += __shfl_xor(s, m);
  float mean = s * (1.f/128.f);
  float e0 = v0-mean, e1 = v1-mean;
  float q = e0*e0 + e1*e1;
  #pragma unroll
  for(int m=32;m>=1;m>>=1) q += __shfl_xor(q, m);
  float inv = rsqrtf(q*(1.f/128.f) + 1e-5f);
  float o0 = e0*inv*g[t] + b[t];
  float o1 = e1*inv*g[t+64] + b[t+64];
  if(SILU){ o0 = fsilu(o0); o1 = fsilu(o1); }
  float* po = out + (size_t)row*DM;
  po[t] = o0; po[t+64] = o1;
}

// ---------- fused: causal dwconv(4)+SiLU -> dbc GEMM (N=40,K=256) -> dt GEMM+softplus.
// block 256 thr, 32 rows/block, grid 64. All operands staged in LDS per 64-d chunk.
__global__ __launch_bounds__(256) void k_xproj(const float* __restrict__ xz,
    const float* __restrict__ cw, const float* __restrict__ cb,
    const float* __restrict__ xpw, const float* __restrict__ dtw,
    const float* __restrict__ dtb_, float* __restrict__ xc_g,
    float* __restrict__ dbc_g, float* __restrict__ dt_g){
  __shared__ float xzs[35][64];     // rows t0-3..t0+31 x 64-d chunk
  __shared__ float As[64][33];      // xc chunk transposed [dk][row]
  __shared__ float Wp[64][41];      // xp_w chunk [dk][nn]
  __shared__ float dtin[32][9];
  __shared__ float dtw_s[256][9];
  int tid = threadIdx.x;
  int row0 = blockIdx.x*32; int b = row0 >> 8; int t0 = row0 & 255;
  int rA = tid & 31, cgA = tid >> 5;        // dbc mapping
  int dlC = tid & 63, rqC = tid >> 6;       // conv mapping
  float acc[5] = {0.f,0.f,0.f,0.f,0.f};
  for(int ch=0; ch<4; ch++){
    int d0 = ch*64;
    __syncthreads();
    for(int u=tid; u<35*64; u+=256){
      int rr = u>>6, dl = u&63;
      int t = t0 + rr - 3;
      xzs[rr][dl] = (t >= 0) ? xz[((size_t)(b*TP)+t)*512 + d0 + dl] : 0.f;
    }
    for(int u=tid; u<40*64; u+=256){
      int nn = u>>6, dk = u&63;
      Wp[dk][nn] = xpw[(size_t)nn*DI + d0 + dk];
    }
    __syncthreads();
    {
      float cw0 = cw[(d0+dlC)*4+0], cw1 = cw[(d0+dlC)*4+1];
      float cw2 = cw[(d0+dlC)*4+2], cw3 = cw[(d0+dlC)*4+3];
      float cbv = cb[d0+dlC];
      #pragma unroll
      for(int i=0;i<8;i++){
        int rr = rqC*8 + i;
        float a = cbv;
        a = fmaf(cw0, xzs[rr+0][dlC], a);
        a = fmaf(cw1, xzs[rr+1][dlC], a);
        a = fmaf(cw2, xzs[rr+2][dlC], a);
        a = fmaf(cw3, xzs[rr+3][dlC], a);
        float v = fsilu(a);
        As[dlC][rr] = v;
        xc_g[((size_t)row0 + rr)*DI + d0 + dlC] = v;
      }
    }
    __syncthreads();
    for(int dk=0; dk<64; dk++){
      float a = As[dk][rA];
      #pragma unroll
      for(int j=0;j<5;j++)
        acc[j] = fmaf(a, Wp[dk][cgA + 8*j], acc[j]);
    }
  }
  dtin[rA][cgA] = acc[0];
  #pragma unroll
  for(int j=1;j<5;j++)
    dbc_g[((size_t)row0 + rA)*40 + cgA + 8*j] = acc[j];
  for(int u=tid; u<256*8; u+=256) dtw_s[u>>3][u&7] = dtw[u];
  __syncthreads();
  {
    int d = tid;
    float bias = dtb_[d];
    float w8[8];
    #pragma unroll
    for(int k=0;k<8;k++) w8[k] = dtw_s[d][k];
    for(int r2=0;r2<32;r2++){
      float a = bias;
      #pragma unroll
      for(int k=0;k<8;k++) a = fmaf(dtin[r2][k], w8[k], a);
      dt_g[((size_t)row0 + r2)*DI + d] = fsoftplus(a);
    }
  }
}

// ---------- chunked selective scan (4 chunks of 64) + D skip + z gate.
// grid = 8b x 32 dblk(8 d); block 512: tid = c*128 + g*16 + n.
// phase1: local scans + end-state E + product P=exp(A*sum dt); barrier;
// phase2: h0 = scan over chunk boundaries, correction g_t = a_t*g_{t-1}.
__global__ __launch_bounds__(512) void k_scan2(const float* __restrict__ dtb,
      const float* __restrict__ xc, const float* __restrict__ xz,
      const float* __restrict__ dbc, const float* __restrict__ A_log,
      const float* __restrict__ Dp, float* __restrict__ y){
  __shared__ float dt_s[TP][8], xc_s[TP][8], z_s[TP][8];
  __shared__ float Bs[TP][16], Cs[TP][16];
  __shared__ float ylocal[TP][8];
  __shared__ float Eb[4][128], Pb[4][128];
  int tid = threadIdx.x;
  int c = tid >> 7, gl = (tid >> 4) & 7, n = tid & 15;
  int dblk = blockIdx.x & 31, b = blockIdx.x >> 5;
  int d0 = dblk*8;
  size_t rbase = (size_t)b*TP;
  for(int u=tid; u<TP*8; u+=512){
    int tt = u>>3, gg = u&7;
    size_t r = rbase + tt;
    dt_s[tt][gg] = dtb[r*DI + d0 + gg];
    xc_s[tt][gg] = xc [r*DI + d0 + gg];
    z_s[tt][gg]  = xz [r*512 + DI + d0 + gg];
  }
  for(int u=tid; u<TP*16; u+=512){
    int tt = u>>4, nn = u&15;
    size_t r = rbase + tt;
    Bs[tt][nn] = dbc[r*40 + 8  + nn];
    Cs[tt][nn] = dbc[r*40 + 24 + nn];
  }
  __syncthreads();
  int d = d0 + gl;
  float An = -__expf(A_log[d*DS + n]);
  float h = 0.f, dtsum = 0.f;
  int tA = c*64;
  for(int i=0;i<64;i++){
    int t = tA + i;
    float dtv = dt_s[t][gl];
    dtsum += dtv;
    float e = __expf(dtv*An);
    h = fmaf(e, h, dtv*xc_s[t][gl]*Bs[t][n]);
    float p = h*Cs[t][n];
    p += __shfl_xor(p,1); p += __shfl_xor(p,2);
    p += __shfl_xor(p,4); p += __shfl_xor(p,8);
    if(n==0) ylocal[t][gl] = p;
  }
  Eb[c][gl*16+n] = h;
  Pb[c][gl*16+n] = __expf(An*dtsum);
  __syncthreads();
  float g = 0.f;
  for(int cp=0; cp<c; cp++)
    g = fmaf(Pb[cp][gl*16+n], g, Eb[cp][gl*16+n]);
  float Dpd = Dp[d];
  for(int i=0;i<64;i++){
    int t = tA + i;
    float e = __expf(dt_s[t][gl]*An);
    g *= e;
    float p = g*Cs[t][n];
    p += __shfl_xor(p,1); p += __shfl_xor(p,2);
    p += __shfl_xor(p,4); p += __shfl_xor(p,8);
    if(n==0){
      float xcv = xc_s[t][gl];
      float yv = ylocal[t][gl] + p + Dpd*xcv;
      y[(rbase+t)*DI + d] = yv * fsilu(z_s[t][gl]);
    }
  }
}

// ---------- masked mean pool + 2-layer classifier. grid = 8, block = 128.
__global__ void k_head(const float* __restrict__ hln, const int* __restrict__ lengths,
                       const float* __restrict__ w1, const float* __restrict__ b1,
                       const float* __restrict__ w2, const float* __restrict__ b2,
                       float* __restrict__ out){
  __shared__ float pooled[DM];
  __shared__ float cbuf[64];
  int b = blockIdx.x, tid = threadIdx.x;
  int tl = lengths[b] >> 1; if(tl < 1) tl = 1;
  float s = 0.f;
  const float* p = hln + (size_t)b*TP*DM + tid;
  for(int t=0;t<tl;t++) s += p[(size_t)t*DM];
  pooled[tid] = s / (float)tl;
  __syncthreads();
  if(tid < 64){
    float a = b1[tid];
    const float* wp = w1 + tid*DM;
    for(int k=0;k<DM;k++) a = fmaf(pooled[k], wp[k], a);
    cbuf[tid] = fsilu(a);
  }
  __syncthreads();
  if(tid < 35){
    float a = b2[tid];
    const float* wp = w2 + tid*64;
    for(int k=0;k<64;k++) a = fmaf(cbuf[k], wp[k], a);
    out[b*35+tid] = a;
  }
}

extern "C" void kernel_launch(void* const* d_in, const int* in_sizes, int n_in,
                              void* d_out, int out_size, void* d_ws, size_t ws_size,
                              hipStream_t stream){
  (void)in_sizes; (void)n_in; (void)out_size; (void)ws_size;
  const float* x        = (const float*)d_in[0];
  const int*   lengths  = (const int*)  d_in[1];
  const float* conv_w1  = (const float*)d_in[2];  const float* conv_b1 = (const float*)d_in[3];
  const float* bn1_s    = (const float*)d_in[4];  const float* bn1_b   = (const float*)d_in[5];
  const float* conv_w2  = (const float*)d_in[6];  const float* conv_b2 = (const float*)d_in[7];
  const float* bn2_s    = (const float*)d_in[8];  const float* bn2_b   = (const float*)d_in[9];
  const float* conv_w3  = (const float*)d_in[10]; const float* conv_b3 = (const float*)d_in[11];
  const float* bn3_s    = (const float*)d_in[12]; const float* bn3_b   = (const float*)d_in[13];
  const float* conv_w4  = (const float*)d_in[14]; const float* conv_b4 = (const float*)d_in[15];
  const float* bn4_s    = (const float*)d_in[16]; const float* bn4_b   = (const float*)d_in[17];
  const float* proj_w   = (const float*)d_in[18]; const float* proj_b  = (const float*)d_in[19];
  const float* proj_ln_s= (const float*)d_in[20]; const float* proj_ln_b=(const float*)d_in[21];
  const float* blk_ln_s = (const float*)d_in[22]; const float* blk_ln_b =(const float*)d_in[23];
  const float* in_w     = (const float*)d_in[24];
  const float* cw       = (const float*)d_in[25]; const float* cbv     = (const float*)d_in[26];
  const float* xp_w     = (const float*)d_in[27];
  const float* dt_w     = (const float*)d_in[28]; const float* dt_b    = (const float*)d_in[29];
  const float* A_log    = (const float*)d_in[30]; const float* Dp      = (const float*)d_in[31];
  const float* out_w    = (const float*)d_in[32];
  const float* pre_ln_s = (const float*)d_in[33]; const float* pre_ln_b= (const float*)d_in[34];
  const float* cls_w1   = (const float*)d_in[35]; const float* cls_b1  = (const float*)d_in[36];
  const float* cls_w2   = (const float*)d_in[37]; const float* cls_b2  = (const float*)d_in[38];

  float* ws   = (float*)d_ws;
  float* R0   = ws;                  // 16,777,216 floats (conv ping)
  float* R1   = R0 + 16777216;       // 16,777,216 floats (conv pong)
  float* xT   = R1 + 16777216;       // 524,288
  float* hbuf = xT + 524288;         // 262,144
  float* lnb  = hbuf + 262144;       // 262,144
  float* xzb  = lnb + 262144;        // 1,048,576
  float* xcb  = xzb + 1048576;       // 524,288
  float* dbcb = xcb + 524288;        // 81,920
  float* dtbb = dbcb + 81920;        // 524,288
  float* yb   = dtbb + 524288;       // 524,288
  float* wt1  = yb + 524288;         // 288
  float* wt2  = wt1 + 288;           // 9,216
  float* wt3  = wt2 + 9216;          // 18,432
  float* wt4  = wt3 + 18432;         // 36,864

  // ---- weight transposes (tiny)
  k_wt<<<(32*1*9 + 255)/256, 256, 0, stream>>>(conv_w1, wt1, 32, 1);
  k_wt<<<(32*32*9 + 255)/256, 256, 0, stream>>>(conv_w2, wt2, 32, 32);
  k_wt<<<(64*32*9 + 255)/256, 256, 0, stream>>>(conv_w3, wt3, 64, 32);
  k_wt<<<(64*64*9 + 255)/256, 256, 0, stream>>>(conv_w4, wt4, 64, 64);

  // ---- frontend
  k_transpose_x<<<2048, 256, 0, stream>>>(x, xT);
  k_conv_t2<1,32,8,1,1><<<8*8*32, 256, 0, stream>>>(xT, wt1, conv_b1, bn1_s, bn1_b, R0, 128, 512);
  k_conv_t2<32,32,8,8,1><<<8*8*32, 256, 0, stream>>>(R0, wt2, conv_b2, bn2_s, bn2_b, R1, 128, 512);
  k_pool2x2<<<(8*32*64*256)/256, 256, 0, stream>>>(R1, R0, 32, 128, 512);
  k_conv_t2<32,64,8,8,2><<<8*4*16*2, 256, 0, stream>>>(R0, wt3, conv_b3, bn3_s, bn3_b, R1, 64, 256);
  k_conv_t2<64,64,8,8,2><<<8*4*16*2, 256, 0, stream>>>(R1, wt4, conv_b4, bn4_s, bn4_b, R0, 64, 256);
  k_pool2x1t<<<(8*256*2048)/256, 256, 0, stream>>>(R0, R1);

  // ---- projection: [2048,2048] @ [128,2048]^T + b -> hbuf, then LN+SiLU
  {
    dim3 g(2, 32);
    k_gemm<0,0><<<g, 256, 0, stream>>>(R1, 2048, proj_w, proj_b, hbuf, 2048, 128, 2048);
  }
  k_ln<1><<<2048, 64, 0, stream>>>(hbuf, proj_ln_s, proj_ln_b, hbuf);

  // ---- mamba layers
  for(int i=0;i<NL;i++){
    k_ln<0><<<2048, 64, 0, stream>>>(hbuf, blk_ln_s + i*DM, blk_ln_b + i*DM, lnb);
    { dim3 g(8, 32);  // xz = ln @ in_w^T : [2048,512]
      k_gemm<0,0><<<g, 256, 0, stream>>>(lnb, DM, in_w + (size_t)i*512*DM, nullptr, xzb, 2048, 512, DM); }
    k_xproj<<<64, 256, 0, stream>>>(xzb, cw + (size_t)i*DI*4, cbv + i*DI,
                                    xp_w + (size_t)i*40*DI, dt_w + (size_t)i*DI*DTR,
                                    dt_b + i*DI, xcb, dbcb, dtbb);
    k_scan2<<<256, 512, 0, stream>>>(dtbb, xcb, xzb, dbcb, A_log + (size_t)i*DI*DS, Dp + i*DI, yb);
    { dim3 g(2, 32);  // hbuf += y @ out_w^T : [2048,128]
      k_gemm<0,1><<<g, 256, 0, stream>>>(yb, DI, out_w + (size_t)i*DM*DI, nullptr, hbuf, 2048, 128, DI); }
  }

  // ---- head
  k_ln<0><<<2048, 64, 0, stream>>>(hbuf, pre_ln_s, pre_ln_b, lnb);
  k_head<<<8, 128, 0, stream>>>(lnb, lengths, cls_w1, cls_b1, cls_w2, cls_b2, (float*)d_out);
}

// Round 4
// 1728.585 us; speedup vs baseline: 2.4104x; 1.0079x over previous
//
#include <hip/hip_runtime.h>
#include <math.h>

#define B_ 8
#define T_ 512
#define FEAT_ 128
#define TP 256          // T' after frontend
#define DM 128          // d_model
#define DI 256          // d_inner
#define DS 16           // d_state
#define DTR 8
#define NL 10

__device__ __forceinline__ float fsilu(float x){ return x / (1.f + __expf(-x)); }
__device__ __forceinline__ float fsoftplus(float x){ return (x > 20.f) ? x : log1pf(__expf(x)); }

// ---------- transpose x [8,512,128] -> xT [8,128,512]
__global__ void k_transpose_x(const float* __restrict__ x, float* __restrict__ xT){
  int idx = blockIdx.x*256 + threadIdx.x;
  if(idx >= B_*FEAT_*T_) return;
  int t = idx % T_; int f = (idx/T_) % FEAT_; int b = idx/(T_*FEAT_);
  xT[idx] = x[((size_t)b*T_ + t)*FEAT_ + f];
}

// ---------- weight transpose [CO,CIN,9] -> [k][CIN][CO]
__global__ void k_wt(const float* __restrict__ w, float* __restrict__ wt, int CO, int CIN){
  int idx = blockIdx.x*256 + threadIdx.x;
  if(idx >= CO*CIN*9) return;
  int k = idx % 9; int ci = (idx/9) % CIN; int co = idx/(9*CIN);
  wt[((size_t)k*CIN + ci)*CO + co] = w[idx];
}

// ---------- tiled direct 3x3 SAME conv + folded BN + SiLU. v3:
// weights staged in LDS ([k][ci][co] layout, wave-uniform float4 broadcast reads).
// block = 256 thr = 4 waves; tile 16x16; wave computes CPW channels.
template<int CIN, int CO, int CPW, int CIG, int COG>
__global__ __launch_bounds__(256) void k_conv_t3(const float* __restrict__ in,
     const float* __restrict__ wt, const float* __restrict__ cb,
     const float* __restrict__ bs, const float* __restrict__ bb,
     float* __restrict__ out, int H, int W){
  constexpr int COB = 4*CPW;
  __shared__ float tile[CIG*342];   // [CIG][18][19]
  __shared__ __align__(16) float wlds[9*CIN*COB];
  int tid = threadIdx.x;
  int lane = tid & 63;
  int wav = __builtin_amdgcn_readfirstlane(tid >> 6);
  int wpr = W >> 4, hpr = H >> 4;
  int idx = blockIdx.x;
  int cog = idx % COG; idx /= COG;
  int tj = idx % wpr; idx /= wpr;
  int ti = idx % hpr; int b = idx / hpr;
  int i0 = ti*16, j0 = tj*16;
  int r = lane >> 2, cg = lane & 3;
  int coBase0 = cog*COB;
  // stage block's weight slice: contiguous co-runs per (k,ci)
  for(int u=tid; u<9*CIN*COB; u+=256){
    int kci = u/COB; int co = u - kci*COB;
    wlds[u] = wt[(size_t)kci*CO + coBase0 + co];
  }
  float acc[CPW][4] = {};
  for(int cig = 0; cig < CIN; cig += CIG){
    __syncthreads();
    for(int u = tid; u < CIG*324; u += 256){
      int ci = u / 324; int rem = u - ci*324; int rr = rem / 18; int cc = rem - rr*18;
      int gi = i0 - 1 + rr, gj = j0 - 1 + cc;
      float v = 0.f;
      if(gi >= 0 && gi < H && gj >= 0 && gj < W)
        v = in[((size_t)(b*CIN + cig + ci)*H + gi)*W + gj];
      tile[ci*342 + rr*19 + cc] = v;
    }
    __syncthreads();
    for(int ci = 0; ci < CIG; ci++){
      float v[3][6];
      #pragma unroll
      for(int kh=0;kh<3;kh++)
        #pragma unroll
        for(int c2=0;c2<6;c2++)
          v[kh][c2] = tile[ci*342 + (r+kh)*19 + cg*4 + c2];
      int ci_g = cig + ci;
      #pragma unroll
      for(int k9=0;k9<9;k9++){
        int kh = k9/3, kw = k9%3;
        const float* wrow = &wlds[(size_t)(k9*CIN + ci_g)*COB + wav*CPW];
        float wv[CPW];
        float4 wA = *(const float4*)wrow;
        wv[0]=wA.x; wv[1]=wA.y; wv[2]=wA.z; wv[3]=wA.w;
        if constexpr (CPW==8){
          float4 wB = *(const float4*)(wrow+4);
          wv[4]=wB.x; wv[5]=wB.y; wv[6]=wB.z; wv[7]=wB.w;
        }
        #pragma unroll
        for(int co=0;co<CPW;co++)
          #pragma unroll
          for(int u2=0;u2<4;u2++)
            acc[co][u2] = fmaf(wv[co], v[kh][kw+u2], acc[co][u2]);
      }
    }
  }
  int i = i0 + r;
  #pragma unroll
  for(int co=0; co<CPW; co++){
    int c = coBase0 + wav*CPW + co;
    float s = bs[c], bias = cb[c]*s + bb[c];
    float4 o;
    o.x = fsilu(acc[co][0]*s + bias);
    o.y = fsilu(acc[co][1]*s + bias);
    o.z = fsilu(acc[co][2]*s + bias);
    o.w = fsilu(acc[co][3]*s + bias);
    *(float4*)&out[((size_t)(b*CO + c)*H + i)*W + j0 + cg*4] = o;
  }
}

// ---------- 2x2 max pool stride 2
__global__ void k_pool2x2(const float* __restrict__ in, float* __restrict__ out,
                          int C, int Hi, int Wi){
  int Ho = Hi>>1, Wo = Wi>>1;
  int total = B_*C*Ho*Wo;
  int idx = blockIdx.x*256 + threadIdx.x;
  if(idx >= total) return;
  int j = idx % Wo; int i = (idx/Wo)%Ho; int c = (idx/(Wo*Ho))%C; int b = idx/(Wo*Ho*C);
  const float* p = in + (((size_t)(b*C+c)*Hi + 2*i)*Wi + 2*j);
  out[idx] = fmaxf(fmaxf(p[0], p[1]), fmaxf(p[Wi], p[Wi+1]));
}

// ---------- fused (2,1)-maxpool + proj GEMM (M=2048,N=128,K=2048) + bias.
// A[m][k] = max over h-pair of R0[b, c, 2hh(+1), t]; m=b*256+t, k=c*32+hh.
// tile 32x64, grid (2, 64). Raw output (LN+SiLU applied after).
__global__ __launch_bounds__(256) void k_proj(const float* __restrict__ R0,
    const float* __restrict__ W, const float* __restrict__ bias,
    float* __restrict__ out){
  __shared__ __align__(16) float As[16][33];
  __shared__ __align__(16) float Ws[16][68];
  int tid = threadIdx.x;
  int n0 = blockIdx.x*64, m0 = blockIdx.y*32;
  int b = m0 >> 8;
  int t_base = m0 & 255;
  int tx = tid&15, ty = tid>>4;
  float acc[2][4] = {};
  for(int k0=0; k0<2048; k0+=16){
    if(tid < 128){
      int row = tid>>2, cq = (tid&3)*4;
      #pragma unroll
      for(int c2=0;c2<4;c2++){
        int k = k0 + cq + c2;
        int c = k>>5, hh = k&31;
        const float* p = R0 + (((size_t)(b*64+c)*64 + 2*hh)*256 + t_base + row);
        As[cq+c2][row] = fmaxf(p[0], p[256]);
      }
    } else {
      int u = tid - 128; int n = u>>1, cq = (u&1)*8;
      const float* wp = W + (size_t)(n0+n)*2048 + k0 + cq;
      float4 v0 = *(const float4*)wp, v1 = *(const float4*)(wp+4);
      Ws[cq+0][n]=v0.x; Ws[cq+1][n]=v0.y; Ws[cq+2][n]=v0.z; Ws[cq+3][n]=v0.w;
      Ws[cq+4][n]=v1.x; Ws[cq+5][n]=v1.y; Ws[cq+6][n]=v1.z; Ws[cq+7][n]=v1.w;
    }
    __syncthreads();
    #pragma unroll
    for(int kk=0;kk<16;kk++){
      float a0 = As[kk][ty*2+0];
      float a1 = As[kk][ty*2+1];
      float4 w4 = *(const float4*)&Ws[kk][tx*4];
      float wv4[4] = {w4.x,w4.y,w4.z,w4.w};
      #pragma unroll
      for(int j=0;j<4;j++){
        acc[0][j] = fmaf(a0, wv4[j], acc[0][j]);
        acc[1][j] = fmaf(a1, wv4[j], acc[1][j]);
      }
    }
    __syncthreads();
  }
  #pragma unroll
  for(int iu=0;iu<2;iu++){
    int m = m0 + ty*2 + iu;
    #pragma unroll
    for(int j=0;j<4;j++){
      int n = n0 + tx*4 + j;
      out[(size_t)m*DM + n] = acc[iu][j] + bias[n];
    }
  }
}

// ---------- LayerNorm over last dim (128), optional SiLU. 1 wave per row.
template<int SILU>
__global__ void k_ln(const float* __restrict__ in, const float* __restrict__ g,
                     const float* __restrict__ b, float* __restrict__ out){
  int row = blockIdx.x;
  int t = threadIdx.x; // 64
  const float* p = in + (size_t)row*DM;
  float v0 = p[t], v1 = p[t+64];
  float s = v0 + v1;
  #pragma unroll
  for(int m=32;m>=1;m>>=1) s += __shfl_xor(s, m);
  float mean = s * (1.f/128.f);
  float e0 = v0-mean, e1 = v1-mean;
  float q = e0*e0 + e1*e1;
  #pragma unroll
  for(int m=32;m>=1;m>>=1) q += __shfl_xor(q, m);
  float inv = rsqrtf(q*(1.f/128.f) + 1e-5f);
  float o0 = e0*inv*g[t] + b[t];
  float o1 = e1*inv*g[t+64] + b[t+64];
  if(SILU){ o0 = fsilu(o0); o1 = fsilu(o1); }
  float* po = out + (size_t)row*DM;
  po[t] = o0; po[t+64] = o1;
}

// ---------- fused LN + xz GEMM: xz[m][n] = LN(hbuf[m]) @ in_w[n]^T.
// tile 32(M) x 64(N), K=128=d_model (full row -> LN in LDS). grid (8, 64).
__global__ __launch_bounds__(256) void k_lnxz(const float* __restrict__ hbuf,
    const float* __restrict__ g, const float* __restrict__ bb,
    const float* __restrict__ W, float* __restrict__ out){
  __shared__ __align__(16) float lns[32][132];
  __shared__ __align__(16) float Ws[16][68];
  int tid = threadIdx.x;
  int n0 = blockIdx.x*64, m0 = blockIdx.y*32;
  for(int u=tid; u<1024; u+=256){
    int row = u>>5, c4 = (u&31)*4;
    float4 v = *(const float4*)(hbuf + (size_t)(m0+row)*DM + c4);
    lns[row][c4] = v.x; lns[row][c4+1] = v.y; lns[row][c4+2] = v.z; lns[row][c4+3] = v.w;
  }
  __syncthreads();
  {
    int lane = tid & 63, wv = tid >> 6;
    for(int rr = wv; rr < 32; rr += 4){
      float v0 = lns[rr][lane], v1 = lns[rr][lane+64];
      float s = v0+v1;
      #pragma unroll
      for(int mm=32;mm>=1;mm>>=1) s += __shfl_xor(s,mm);
      float mean = s*(1.f/128.f);
      float e0 = v0-mean, e1 = v1-mean;
      float q = e0*e0+e1*e1;
      #pragma unroll
      for(int mm=32;mm>=1;mm>>=1) q += __shfl_xor(q,mm);
      float inv = rsqrtf(q*(1.f/128.f)+1e-5f);
      lns[rr][lane]    = e0*inv*g[lane] + bb[lane];
      lns[rr][lane+64] = e1*inv*g[lane+64] + bb[lane+64];
    }
  }
  __syncthreads();
  int tx = tid&15, ty = tid>>4;
  float acc[2][4] = {};
  for(int k0=0;k0<128;k0+=16){
    {
      int n = tid>>2, c4 = (tid&3)*4;
      float4 v = *(const float4*)(W + (size_t)(n0+n)*DM + k0 + c4);
      Ws[c4+0][n]=v.x; Ws[c4+1][n]=v.y; Ws[c4+2][n]=v.z; Ws[c4+3][n]=v.w;
    }
    __syncthreads();
    #pragma unroll
    for(int kk=0;kk<16;kk++){
      float a0 = lns[ty*2+0][k0+kk];
      float a1 = lns[ty*2+1][k0+kk];
      float4 w4 = *(const float4*)&Ws[kk][tx*4];
      float wv4[4] = {w4.x,w4.y,w4.z,w4.w};
      #pragma unroll
      for(int j=0;j<4;j++){
        acc[0][j] = fmaf(a0, wv4[j], acc[0][j]);
        acc[1][j] = fmaf(a1, wv4[j], acc[1][j]);
      }
    }
    __syncthreads();
  }
  #pragma unroll
  for(int iu=0;iu<2;iu++){
    int m = m0 + ty*2 + iu;
    float* po = out + (size_t)m*512 + n0 + tx*4;
    #pragma unroll
    for(int j=0;j<4;j++) po[j] = acc[iu][j];
  }
}

// ---------- fused: causal dwconv(4)+SiLU -> dbc GEMM -> dt GEMM+softplus.
// 16 rows/block, grid 128, 256 thr.
__global__ __launch_bounds__(256) void k_xproj16(const float* __restrict__ xz,
    const float* __restrict__ cw, const float* __restrict__ cb,
    const float* __restrict__ xpw, const float* __restrict__ dtw,
    const float* __restrict__ dtb_, float* __restrict__ xc_g,
    float* __restrict__ dbc_g, float* __restrict__ dt_g){
  __shared__ float xzs[19][64];
  __shared__ float As[64][17];
  __shared__ float Wp[64][41];
  __shared__ float dtin[16][9];
  __shared__ float dtw_s[256][9];
  int tid = threadIdx.x;
  int row0 = blockIdx.x*16; int b = row0 >> 8; int t0 = row0 & 255;
  int rA = tid & 15, cgA = tid >> 4;
  int dlC = tid & 63, rqC = tid >> 6;
  float acc[3] = {0.f,0.f,0.f};
  for(int ch=0; ch<4; ch++){
    int d0 = ch*64;
    __syncthreads();
    for(int u=tid; u<19*64; u+=256){
      int rr = u>>6, dl = u&63;
      int t = t0 + rr - 3;
      xzs[rr][dl] = (t >= 0) ? xz[((size_t)(b*TP)+t)*512 + d0 + dl] : 0.f;
    }
    for(int u=tid; u<40*64; u+=256){
      int nn = u>>6, dk = u&63;
      Wp[dk][nn] = xpw[(size_t)nn*DI + d0 + dk];
    }
    __syncthreads();
    {
      float cw0 = cw[(d0+dlC)*4+0], cw1 = cw[(d0+dlC)*4+1];
      float cw2 = cw[(d0+dlC)*4+2], cw3 = cw[(d0+dlC)*4+3];
      float cbv = cb[d0+dlC];
      #pragma unroll
      for(int i=0;i<4;i++){
        int rr = rqC*4 + i;
        float a = cbv;
        a = fmaf(cw0, xzs[rr+0][dlC], a);
        a = fmaf(cw1, xzs[rr+1][dlC], a);
        a = fmaf(cw2, xzs[rr+2][dlC], a);
        a = fmaf(cw3, xzs[rr+3][dlC], a);
        float v = fsilu(a);
        As[dlC][rr] = v;
        xc_g[((size_t)row0 + rr)*DI + d0 + dlC] = v;
      }
    }
    __syncthreads();
    for(int dk=0; dk<64; dk++){
      float a = As[dk][rA];
      acc[0] = fmaf(a, Wp[dk][cgA], acc[0]);
      acc[1] = fmaf(a, Wp[dk][cgA+16], acc[1]);
      if(cgA < 8) acc[2] = fmaf(a, Wp[dk][cgA+32], acc[2]);
    }
  }
  if(cgA < 8) dtin[rA][cgA] = acc[0];
  else dbc_g[((size_t)row0 + rA)*40 + cgA] = acc[0];
  dbc_g[((size_t)row0 + rA)*40 + cgA + 16] = acc[1];
  if(cgA < 8) dbc_g[((size_t)row0 + rA)*40 + cgA + 32] = acc[2];
  for(int u=tid; u<256*8; u+=256) dtw_s[u>>3][u&7] = dtw[u];
  __syncthreads();
  {
    int d = tid;
    float bias = dtb_[d];
    float w8[8];
    #pragma unroll
    for(int k=0;k<8;k++) w8[k] = dtw_s[d][k];
    for(int r2=0;r2<16;r2++){
      float a = bias;
      #pragma unroll
      for(int k=0;k<8;k++) a = fmaf(dtin[r2][k], w8[k], a);
      dt_g[((size_t)row0 + r2)*DI + d] = fsoftplus(a);
    }
  }
}

// ---------- chunked selective scan (4 chunks of 64) + D skip + z gate.
__global__ __launch_bounds__(512) void k_scan2(const float* __restrict__ dtb,
      const float* __restrict__ xc, const float* __restrict__ xz,
      const float* __restrict__ dbc, const float* __restrict__ A_log,
      const float* __restrict__ Dp, float* __restrict__ y){
  __shared__ float dt_s[TP][8], xc_s[TP][8], z_s[TP][8];
  __shared__ float Bs[TP][16], Cs[TP][16];
  __shared__ float ylocal[TP][8];
  __shared__ float Eb[4][128], Pb[4][128];
  int tid = threadIdx.x;
  int c = tid >> 7, gl = (tid >> 4) & 7, n = tid & 15;
  int dblk = blockIdx.x & 31, b = blockIdx.x >> 5;
  int d0 = dblk*8;
  size_t rbase = (size_t)b*TP;
  for(int u=tid; u<TP*8; u+=512){
    int tt = u>>3, gg = u&7;
    size_t r = rbase + tt;
    dt_s[tt][gg] = dtb[r*DI + d0 + gg];
    xc_s[tt][gg] = xc [r*DI + d0 + gg];
    z_s[tt][gg]  = xz [r*512 + DI + d0 + gg];
  }
  for(int u=tid; u<TP*16; u+=512){
    int tt = u>>4, nn = u&15;
    size_t r = rbase + tt;
    Bs[tt][nn] = dbc[r*40 + 8  + nn];
    Cs[tt][nn] = dbc[r*40 + 24 + nn];
  }
  __syncthreads();
  int d = d0 + gl;
  float An = -__expf(A_log[d*DS + n]);
  float h = 0.f, dtsum = 0.f;
  int tA = c*64;
  for(int i=0;i<64;i++){
    int t = tA + i;
    float dtv = dt_s[t][gl];
    dtsum += dtv;
    float e = __expf(dtv*An);
    h = fmaf(e, h, dtv*xc_s[t][gl]*Bs[t][n]);
    float p = h*Cs[t][n];
    p += __shfl_xor(p,1); p += __shfl_xor(p,2);
    p += __shfl_xor(p,4); p += __shfl_xor(p,8);
    if(n==0) ylocal[t][gl] = p;
  }
  Eb[c][gl*16+n] = h;
  Pb[c][gl*16+n] = __expf(An*dtsum);
  __syncthreads();
  float g = 0.f;
  for(int cp=0; cp<c; cp++)
    g = fmaf(Pb[cp][gl*16+n], g, Eb[cp][gl*16+n]);
  float Dpd = Dp[d];
  for(int i=0;i<64;i++){
    int t = tA + i;
    float e = __expf(dt_s[t][gl]*An);
    g *= e;
    float p = g*Cs[t][n];
    p += __shfl_xor(p,1); p += __shfl_xor(p,2);
    p += __shfl_xor(p,4); p += __shfl_xor(p,8);
    if(n==0){
      float xcv = xc_s[t][gl];
      float yv = ylocal[t][gl] + p + Dpd*xcv;
      y[(rbase+t)*DI + d] = yv * fsilu(z_s[t][gl]);
    }
  }
}

// ---------- out-proj GEMM + residual: C[m][n] += A[m][k] @ W[n][k]^T.
// M=2048,N=128,K=256; tile 32x64; grid (2, 64).
__global__ __launch_bounds__(256) void k_out32(const float* __restrict__ A,
    const float* __restrict__ W, float* __restrict__ C){
  __shared__ __align__(16) float As[16][33];
  __shared__ __align__(16) float Ws[16][68];
  int tid = threadIdx.x;
  int n0 = blockIdx.x*64, m0 = blockIdx.y*32;
  int tx = tid&15, ty = tid>>4;
  float acc[2][4] = {};
  for(int k0=0;k0<256;k0+=16){
    if(tid<128){
      int row = tid>>2, cq = (tid&3)*4;
      float4 v = *(const float4*)(A + (size_t)(m0+row)*DI + k0 + cq);
      As[cq+0][row]=v.x; As[cq+1][row]=v.y; As[cq+2][row]=v.z; As[cq+3][row]=v.w;
    } else {
      int u = tid-128; int n = u>>1, cq = (u&1)*8;
      const float* wp = W + (size_t)(n0+n)*DI + k0 + cq;
      float4 v0 = *(const float4*)wp, v1 = *(const float4*)(wp+4);
      Ws[cq+0][n]=v0.x; Ws[cq+1][n]=v0.y; Ws[cq+2][n]=v0.z; Ws[cq+3][n]=v0.w;
      Ws[cq+4][n]=v1.x; Ws[cq+5][n]=v1.y; Ws[cq+6][n]=v1.z; Ws[cq+7][n]=v1.w;
    }
    __syncthreads();
    #pragma unroll
    for(int kk=0;kk<16;kk++){
      float a0 = As[kk][ty*2+0];
      float a1 = As[kk][ty*2+1];
      float4 w4 = *(const float4*)&Ws[kk][tx*4];
      float wv4[4] = {w4.x,w4.y,w4.z,w4.w};
      #pragma unroll
      for(int j=0;j<4;j++){
        acc[0][j] = fmaf(a0, wv4[j], acc[0][j]);
        acc[1][j] = fmaf(a1, wv4[j], acc[1][j]);
      }
    }
    __syncthreads();
  }
  #pragma unroll
  for(int iu=0;iu<2;iu++){
    int m = m0 + ty*2 + iu;
    #pragma unroll
    for(int j=0;j<4;j++){
      int n = n0 + tx*4 + j;
      size_t o = (size_t)m*DM + n;
      C[o] += acc[iu][j];
    }
  }
}

// ---------- masked mean pool + 2-layer classifier. grid = 8, block = 128.
__global__ void k_head(const float* __restrict__ hln, const int* __restrict__ lengths,
                       const float* __restrict__ w1, const float* __restrict__ b1,
                       const float* __restrict__ w2, const float* __restrict__ b2,
                       float* __restrict__ out){
  __shared__ float pooled[DM];
  __shared__ float cbuf[64];
  int b = blockIdx.x, tid = threadIdx.x;
  int tl = lengths[b] >> 1; if(tl < 1) tl = 1;
  float s = 0.f;
  const float* p = hln + (size_t)b*TP*DM + tid;
  for(int t=0;t<tl;t++) s += p[(size_t)t*DM];
  pooled[tid] = s / (float)tl;
  __syncthreads();
  if(tid < 64){
    float a = b1[tid];
    const float* wp = w1 + tid*DM;
    for(int k=0;k<DM;k++) a = fmaf(pooled[k], wp[k], a);
    cbuf[tid] = fsilu(a);
  }
  __syncthreads();
  if(tid < 35){
    float a = b2[tid];
    const float* wp = w2 + tid*64;
    for(int k=0;k<64;k++) a = fmaf(cbuf[k], wp[k], a);
    out[b*35+tid] = a;
  }
}

extern "C" void kernel_launch(void* const* d_in, const int* in_sizes, int n_in,
                              void* d_out, int out_size, void* d_ws, size_t ws_size,
                              hipStream_t stream){
  (void)in_sizes; (void)n_in; (void)out_size; (void)ws_size;
  const float* x        = (const float*)d_in[0];
  const int*   lengths  = (const int*)  d_in[1];
  const float* conv_w1  = (const float*)d_in[2];  const float* conv_b1 = (const float*)d_in[3];
  const float* bn1_s    = (const float*)d_in[4];  const float* bn1_b   = (const float*)d_in[5];
  const float* conv_w2  = (const float*)d_in[6];  const float* conv_b2 = (const float*)d_in[7];
  const float* bn2_s    = (const float*)d_in[8];  const float* bn2_b   = (const float*)d_in[9];
  const float* conv_w3  = (const float*)d_in[10]; const float* conv_b3 = (const float*)d_in[11];
  const float* bn3_s    = (const float*)d_in[12]; const float* bn3_b   = (const float*)d_in[13];
  const float* conv_w4  = (const float*)d_in[14]; const float* conv_b4 = (const float*)d_in[15];
  const float* bn4_s    = (const float*)d_in[16]; const float* bn4_b   = (const float*)d_in[17];
  const float* proj_w   = (const float*)d_in[18]; const float* proj_b  = (const float*)d_in[19];
  const float* proj_ln_s= (const float*)d_in[20]; const float* proj_ln_b=(const float*)d_in[21];
  const float* blk_ln_s = (const float*)d_in[22]; const float* blk_ln_b =(const float*)d_in[23];
  const float* in_w     = (const float*)d_in[24];
  const float* cw       = (const float*)d_in[25]; const float* cbv     = (const float*)d_in[26];
  const float* xp_w     = (const float*)d_in[27];
  const float* dt_w     = (const float*)d_in[28]; const float* dt_b    = (const float*)d_in[29];
  const float* A_log    = (const float*)d_in[30]; const float* Dp      = (const float*)d_in[31];
  const float* out_w    = (const float*)d_in[32];
  const float* pre_ln_s = (const float*)d_in[33]; const float* pre_ln_b= (const float*)d_in[34];
  const float* cls_w1   = (const float*)d_in[35]; const float* cls_b1  = (const float*)d_in[36];
  const float* cls_w2   = (const float*)d_in[37]; const float* cls_b2  = (const float*)d_in[38];

  float* ws   = (float*)d_ws;
  float* R0   = ws;                  // 16,777,216 floats (conv ping)
  float* R1   = R0 + 16777216;       // 16,777,216 floats (conv pong)
  float* xT   = R1 + 16777216;       // 524,288
  float* hbuf = xT + 524288;         // 262,144
  float* lnb  = hbuf + 262144;       // 262,144
  float* xzb  = lnb + 262144;        // 1,048,576
  float* xcb  = xzb + 1048576;       // 524,288
  float* dbcb = xcb + 524288;        // 81,920
  float* dtbb = dbcb + 81920;        // 524,288
  float* yb   = dtbb + 524288;       // 524,288
  float* wt1  = yb + 524288;         // 288
  float* wt2  = wt1 + 288;           // 9,216
  float* wt3  = wt2 + 9216;          // 18,432
  float* wt4  = wt3 + 18432;         // 36,864

  // ---- weight transposes (tiny) to [k][ci][co]
  k_wt<<<(32*1*9 + 255)/256, 256, 0, stream>>>(conv_w1, wt1, 32, 1);
  k_wt<<<(32*32*9 + 255)/256, 256, 0, stream>>>(conv_w2, wt2, 32, 32);
  k_wt<<<(64*32*9 + 255)/256, 256, 0, stream>>>(conv_w3, wt3, 64, 32);
  k_wt<<<(64*64*9 + 255)/256, 256, 0, stream>>>(conv_w4, wt4, 64, 64);

  // ---- frontend
  k_transpose_x<<<2048, 256, 0, stream>>>(x, xT);
  k_conv_t3<1,32,8,1,1><<<8*8*32, 256, 0, stream>>>(xT, wt1, conv_b1, bn1_s, bn1_b, R0, 128, 512);
  k_conv_t3<32,32,8,8,1><<<8*8*32, 256, 0, stream>>>(R0, wt2, conv_b2, bn2_s, bn2_b, R1, 128, 512);
  k_pool2x2<<<(8*32*64*256)/256, 256, 0, stream>>>(R1, R0, 32, 128, 512);
  k_conv_t3<32,64,8,8,2><<<8*4*16*2, 256, 0, stream>>>(R0, wt3, conv_b3, bn3_s, bn3_b, R1, 64, 256);
  k_conv_t3<64,64,4,8,4><<<8*4*16*4, 256, 0, stream>>>(R1, wt4, conv_b4, bn4_s, bn4_b, R0, 64, 256);

  // ---- fused pool(2,1) + projection GEMM -> lnb (raw), then LN+SiLU -> hbuf
  {
    dim3 g(2, 64);
    k_proj<<<g, 256, 0, stream>>>(R0, proj_w, proj_b, lnb);
  }
  k_ln<1><<<2048, 64, 0, stream>>>(lnb, proj_ln_s, proj_ln_b, hbuf);

  // ---- mamba layers
  for(int i=0;i<NL;i++){
    { dim3 g(8, 64);  // fused LN + xz GEMM
      k_lnxz<<<g, 256, 0, stream>>>(hbuf, blk_ln_s + i*DM, blk_ln_b + i*DM,
                                    in_w + (size_t)i*512*DM, xzb); }
    k_xproj16<<<128, 256, 0, stream>>>(xzb, cw + (size_t)i*DI*4, cbv + i*DI,
                                       xp_w + (size_t)i*40*DI, dt_w + (size_t)i*DI*DTR,
                                       dt_b + i*DI, xcb, dbcb, dtbb);
    k_scan2<<<256, 512, 0, stream>>>(dtbb, xcb, xzb, dbcb, A_log + (size_t)i*DI*DS, Dp + i*DI, yb);
    { dim3 g(2, 64);  // out-proj + residual
      k_out32<<<g, 256, 0, stream>>>(yb, out_w + (size_t)i*DM*DI, hbuf); }
  }

  // ---- head
  k_ln<0><<<2048, 64, 0, stream>>>(hbuf, pre_ln_s, pre_ln_b, lnb);
  k_head<<<8, 128, 0, stream>>>(lnb, lengths, cls_w1, cls_b1, cls_w2, cls_b2, (float*)d_out);
}

// Round 5
// 1477.670 us; speedup vs baseline: 2.8197x; 1.1698x over previous
//
#include <hip/hip_runtime.h>
#include <math.h>

#define B_ 8
#define T_ 512
#define FEAT_ 128
#define TP 256          // T' after frontend
#define DM 128          // d_model
#define DI 256          // d_inner
#define DS 16           // d_state
#define DTR 8
#define NL 10

__device__ __forceinline__ float fsilu(float x){ return x / (1.f + __expf(-x)); }
__device__ __forceinline__ float fsoftplus(float x){ return (x > 20.f) ? x : log1pf(__expf(x)); }

// ---------- transpose x [8,512,128] -> xT [8,128,512]
__global__ void k_transpose_x(const float* __restrict__ x, float* __restrict__ xT){
  int idx = blockIdx.x*256 + threadIdx.x;
  if(idx >= B_*FEAT_*T_) return;
  int t = idx % T_; int f = (idx/T_) % FEAT_; int b = idx/(T_*FEAT_);
  xT[idx] = x[((size_t)b*T_ + t)*FEAT_ + f];
}

// ---------- all 4 conv-weight transposes in one launch.
// out layout: [ci][slot][72] where slot = co/8, within = (co%8)*9 + k (16B-aligned runs)
__device__ __forceinline__ void wt_one(const float* __restrict__ w, float* __restrict__ o,
                                       int idx, int CO, int CIN){
  int k = idx % 9; int ci = (idx/9) % CIN; int co = idx/(9*CIN);
  o[((size_t)(ci*(CO>>3) + (co>>3)))*72 + (co&7)*9 + k] = w[idx];
}
__global__ void k_wt_all(const float* __restrict__ w1, const float* __restrict__ w2,
                         const float* __restrict__ w3, const float* __restrict__ w4,
                         float* __restrict__ o1, float* __restrict__ o2,
                         float* __restrict__ o3, float* __restrict__ o4){
  int idx = blockIdx.x*256 + threadIdx.x;
  if(idx < 288){ wt_one(w1, o1, idx, 32, 1); return; }
  idx -= 288;
  if(idx < 9216){ wt_one(w2, o2, idx, 32, 32); return; }
  idx -= 9216;
  if(idx < 18432){ wt_one(w3, o3, idx, 64, 32); return; }
  idx -= 18432;
  if(idx < 36864){ wt_one(w4, o4, idx, 64, 64); return; }
}

// ---------- tiled direct 3x3 SAME conv + folded BN + SiLU. v4:
// stride-20 LDS rows; per-(ci,kh) reads = 2 aligned ds_read_b128 (conflict-free:
// quad = (5R+cg) mod 8 is exactly 8 lanes/quad). Weights: contiguous 72-float
// block per (ci, wave-slot), wave-uniform dwordx4 loads.
template<int CIN, int CO, int CPW, int CIG, int COG>
__global__ __launch_bounds__(256) void k_conv_t4(const float* __restrict__ in,
     const float* __restrict__ wt, const float* __restrict__ cb,
     const float* __restrict__ bs, const float* __restrict__ bb,
     float* __restrict__ out, int H, int W){
  constexpr int NS = CO/CPW;            // total wave-slots
  __shared__ __align__(16) float tile[CIG*360];   // [CIG][18][20]
  int tid = threadIdx.x;
  int lane = tid & 63;
  int wav = __builtin_amdgcn_readfirstlane(tid >> 6);
  int wpr = W >> 4, hpr = H >> 4;
  int idx = blockIdx.x;
  int cog = idx % COG; idx /= COG;
  int tj = idx % wpr; idx /= wpr;
  int ti = idx % hpr; int b = idx / hpr;
  int i0 = ti*16, j0 = tj*16;
  int r = lane >> 2, cg = lane & 3;
  int wslot = cog*4 + wav;
  const float* wbase = wt + (size_t)wslot*72;
  float acc[CPW][4] = {};
  for(int cig = 0; cig < CIN; cig += CIG){
    __syncthreads();
    for(int u = tid; u < CIG*324; u += 256){
      int ci = u / 324; int rem = u - ci*324; int rr = rem / 18; int cc = rem - rr*18;
      int gi = i0 - 1 + rr, gj = j0 - 1 + cc;
      float v = 0.f;
      if(gi >= 0 && gi < H && gj >= 0 && gj < W)
        v = in[((size_t)(b*CIN + cig + ci)*H + gi)*W + gj];
      tile[ci*360 + rr*20 + cc] = v;
    }
    __syncthreads();
    for(int ci = 0; ci < CIG; ci++){
      // 72 weights for this (ci, wave-slot): 18 aligned float4 loads (uniform addr)
      const float4* wp4 = (const float4*)(wbase + (size_t)(cig+ci)*(NS*72));
      float4 w4q[18];
      #pragma unroll
      for(int q=0;q<18;q++) w4q[q] = wp4[q];
      const float* wf = (const float*)w4q;
      #pragma unroll
      for(int kh=0;kh<3;kh++){
        float4 a = *(const float4*)&tile[ci*360 + (r+kh)*20 + cg*4];
        float4 bv = *(const float4*)&tile[ci*360 + (r+kh)*20 + cg*4 + 4];
        float v[6] = {a.x,a.y,a.z,a.w,bv.x,bv.y};
        #pragma unroll
        for(int co=0;co<CPW;co++){
          #pragma unroll
          for(int kw=0;kw<3;kw++){
            float wv = wf[co*9 + kh*3 + kw];
            #pragma unroll
            for(int u2=0;u2<4;u2++)
              acc[co][u2] = fmaf(wv, v[kw+u2], acc[co][u2]);
          }
        }
      }
    }
  }
  int i = i0 + r;
  #pragma unroll
  for(int co=0; co<CPW; co++){
    int c = cog*(4*CPW) + wav*CPW + co;
    float s = bs[c], bias = cb[c]*s + bb[c];
    float4 o;
    o.x = fsilu(acc[co][0]*s + bias);
    o.y = fsilu(acc[co][1]*s + bias);
    o.z = fsilu(acc[co][2]*s + bias);
    o.w = fsilu(acc[co][3]*s + bias);
    *(float4*)&out[((size_t)(b*CO + c)*H + i)*W + j0 + cg*4] = o;
  }
}

// ---------- 2x2 max pool stride 2
__global__ void k_pool2x2(const float* __restrict__ in, float* __restrict__ out,
                          int C, int Hi, int Wi){
  int Ho = Hi>>1, Wo = Wi>>1;
  int total = B_*C*Ho*Wo;
  int idx = blockIdx.x*256 + threadIdx.x;
  if(idx >= total) return;
  int j = idx % Wo; int i = (idx/Wo)%Ho; int c = (idx/(Wo*Ho))%C; int b = idx/(Wo*Ho*C);
  const float* p = in + (((size_t)(b*C+c)*Hi + 2*i)*Wi + 2*j);
  out[idx] = fmaxf(fmaxf(p[0], p[1]), fmaxf(p[Wi], p[Wi+1]));
}

// ---------- fused (2,1)-maxpool + proj GEMM (M=2048,N=128,K=2048) + bias.
__global__ __launch_bounds__(256) void k_proj(const float* __restrict__ R0,
    const float* __restrict__ W, const float* __restrict__ bias,
    float* __restrict__ out){
  __shared__ __align__(16) float As[16][33];
  __shared__ __align__(16) float Ws[16][68];
  int tid = threadIdx.x;
  int n0 = blockIdx.x*64, m0 = blockIdx.y*32;
  int b = m0 >> 8;
  int t_base = m0 & 255;
  int tx = tid&15, ty = tid>>4;
  float acc[2][4] = {};
  for(int k0=0; k0<2048; k0+=16){
    if(tid < 128){
      int row = tid>>2, cq = (tid&3)*4;
      #pragma unroll
      for(int c2=0;c2<4;c2++){
        int k = k0 + cq + c2;
        int c = k>>5, hh = k&31;
        const float* p = R0 + (((size_t)(b*64+c)*64 + 2*hh)*256 + t_base + row);
        As[cq+c2][row] = fmaxf(p[0], p[256]);
      }
    } else {
      int u = tid - 128; int n = u>>1, cq = (u&1)*8;
      const float* wp = W + (size_t)(n0+n)*2048 + k0 + cq;
      float4 v0 = *(const float4*)wp, v1 = *(const float4*)(wp+4);
      Ws[cq+0][n]=v0.x; Ws[cq+1][n]=v0.y; Ws[cq+2][n]=v0.z; Ws[cq+3][n]=v0.w;
      Ws[cq+4][n]=v1.x; Ws[cq+5][n]=v1.y; Ws[cq+6][n]=v1.z; Ws[cq+7][n]=v1.w;
    }
    __syncthreads();
    #pragma unroll
    for(int kk=0;kk<16;kk++){
      float a0 = As[kk][ty*2+0];
      float a1 = As[kk][ty*2+1];
      float4 w4 = *(const float4*)&Ws[kk][tx*4];
      float wv4[4] = {w4.x,w4.y,w4.z,w4.w};
      #pragma unroll
      for(int j=0;j<4;j++){
        acc[0][j] = fmaf(a0, wv4[j], acc[0][j]);
        acc[1][j] = fmaf(a1, wv4[j], acc[1][j]);
      }
    }
    __syncthreads();
  }
  #pragma unroll
  for(int iu=0;iu<2;iu++){
    int m = m0 + ty*2 + iu;
    #pragma unroll
    for(int j=0;j<4;j++){
      int n = n0 + tx*4 + j;
      out[(size_t)m*DM + n] = acc[iu][j] + bias[n];
    }
  }
}

// ---------- LayerNorm over last dim (128), optional SiLU. 1 wave per row.
template<int SILU>
__global__ void k_ln(const float* __restrict__ in, const float* __restrict__ g,
                     const float* __restrict__ b, float* __restrict__ out){
  int row = blockIdx.x;
  int t = threadIdx.x; // 64
  const float* p = in + (size_t)row*DM;
  float v0 = p[t], v1 = p[t+64];
  float s = v0 + v1;
  #pragma unroll
  for(int m=32;m>=1;m>>=1) s += __shfl_xor(s, m);
  float mean = s * (1.f/128.f);
  float e0 = v0-mean, e1 = v1-mean;
  float q = e0*e0 + e1*e1;
  #pragma unroll
  for(int m=32;m>=1;m>>=1) q += __shfl_xor(q, m);
  float inv = rsqrtf(q*(1.f/128.f) + 1e-5f);
  float o0 = e0*inv*g[t] + b[t];
  float o1 = e1*inv*g[t+64] + b[t+64];
  if(SILU){ o0 = fsilu(o0); o1 = fsilu(o1); }
  float* po = out + (size_t)row*DM;
  po[t] = o0; po[t+64] = o1;
}

// ---------- fused LN + xz GEMM: xz[m][n] = LN(hbuf[m]) @ in_w[n]^T.
__global__ __launch_bounds__(256) void k_lnxz(const float* __restrict__ hbuf,
    const float* __restrict__ g, const float* __restrict__ bb,
    const float* __restrict__ W, float* __restrict__ out){
  __shared__ __align__(16) float lns[32][132];
  __shared__ __align__(16) float Ws[16][68];
  int tid = threadIdx.x;
  int n0 = blockIdx.x*64, m0 = blockIdx.y*32;
  for(int u=tid; u<1024; u+=256){
    int row = u>>5, c4 = (u&31)*4;
    float4 v = *(const float4*)(hbuf + (size_t)(m0+row)*DM + c4);
    lns[row][c4] = v.x; lns[row][c4+1] = v.y; lns[row][c4+2] = v.z; lns[row][c4+3] = v.w;
  }
  __syncthreads();
  {
    int lane = tid & 63, wv = tid >> 6;
    for(int rr = wv; rr < 32; rr += 4){
      float v0 = lns[rr][lane], v1 = lns[rr][lane+64];
      float s = v0+v1;
      #pragma unroll
      for(int mm=32;mm>=1;mm>>=1) s += __shfl_xor(s,mm);
      float mean = s*(1.f/128.f);
      float e0 = v0-mean, e1 = v1-mean;
      float q = e0*e0+e1*e1;
      #pragma unroll
      for(int mm=32;mm>=1;mm>>=1) q += __shfl_xor(q,mm);
      float inv = rsqrtf(q*(1.f/128.f)+1e-5f);
      lns[rr][lane]    = e0*inv*g[lane] + bb[lane];
      lns[rr][lane+64] = e1*inv*g[lane+64] + bb[lane+64];
    }
  }
  __syncthreads();
  int tx = tid&15, ty = tid>>4;
  float acc[2][4] = {};
  for(int k0=0;k0<128;k0+=16){
    {
      int n = tid>>2, c4 = (tid&3)*4;
      float4 v = *(const float4*)(W + (size_t)(n0+n)*DM + k0 + c4);
      Ws[c4+0][n]=v.x; Ws[c4+1][n]=v.y; Ws[c4+2][n]=v.z; Ws[c4+3][n]=v.w;
    }
    __syncthreads();
    #pragma unroll
    for(int kk=0;kk<16;kk++){
      float a0 = lns[ty*2+0][k0+kk];
      float a1 = lns[ty*2+1][k0+kk];
      float4 w4 = *(const float4*)&Ws[kk][tx*4];
      float wv4[4] = {w4.x,w4.y,w4.z,w4.w};
      #pragma unroll
      for(int j=0;j<4;j++){
        acc[0][j] = fmaf(a0, wv4[j], acc[0][j]);
        acc[1][j] = fmaf(a1, wv4[j], acc[1][j]);
      }
    }
    __syncthreads();
  }
  #pragma unroll
  for(int iu=0;iu<2;iu++){
    int m = m0 + ty*2 + iu;
    float* po = out + (size_t)m*512 + n0 + tx*4;
    #pragma unroll
    for(int j=0;j<4;j++) po[j] = acc[iu][j];
  }
}

// ---------- fused: causal dwconv(4)+SiLU -> dbc GEMM -> dt GEMM+softplus.
__global__ __launch_bounds__(256) void k_xproj16(const float* __restrict__ xz,
    const float* __restrict__ cw, const float* __restrict__ cb,
    const float* __restrict__ xpw, const float* __restrict__ dtw,
    const float* __restrict__ dtb_, float* __restrict__ xc_g,
    float* __restrict__ dbc_g, float* __restrict__ dt_g){
  __shared__ float xzs[19][64];
  __shared__ float As[64][17];
  __shared__ float Wp[64][41];
  __shared__ float dtin[16][9];
  __shared__ float dtw_s[256][9];
  int tid = threadIdx.x;
  int row0 = blockIdx.x*16; int b = row0 >> 8; int t0 = row0 & 255;
  int rA = tid & 15, cgA = tid >> 4;
  int dlC = tid & 63, rqC = tid >> 6;
  float acc[3] = {0.f,0.f,0.f};
  for(int ch=0; ch<4; ch++){
    int d0 = ch*64;
    __syncthreads();
    for(int u=tid; u<19*64; u+=256){
      int rr = u>>6, dl = u&63;
      int t = t0 + rr - 3;
      xzs[rr][dl] = (t >= 0) ? xz[((size_t)(b*TP)+t)*512 + d0 + dl] : 0.f;
    }
    for(int u=tid; u<40*64; u+=256){
      int nn = u>>6, dk = u&63;
      Wp[dk][nn] = xpw[(size_t)nn*DI + d0 + dk];
    }
    __syncthreads();
    {
      float cw0 = cw[(d0+dlC)*4+0], cw1 = cw[(d0+dlC)*4+1];
      float cw2 = cw[(d0+dlC)*4+2], cw3 = cw[(d0+dlC)*4+3];
      float cbv = cb[d0+dlC];
      #pragma unroll
      for(int i=0;i<4;i++){
        int rr = rqC*4 + i;
        float a = cbv;
        a = fmaf(cw0, xzs[rr+0][dlC], a);
        a = fmaf(cw1, xzs[rr+1][dlC], a);
        a = fmaf(cw2, xzs[rr+2][dlC], a);
        a = fmaf(cw3, xzs[rr+3][dlC], a);
        float v = fsilu(a);
        As[dlC][rr] = v;
        xc_g[((size_t)row0 + rr)*DI + d0 + dlC] = v;
      }
    }
    __syncthreads();
    for(int dk=0; dk<64; dk++){
      float a = As[dk][rA];
      acc[0] = fmaf(a, Wp[dk][cgA], acc[0]);
      acc[1] = fmaf(a, Wp[dk][cgA+16], acc[1]);
      if(cgA < 8) acc[2] = fmaf(a, Wp[dk][cgA+32], acc[2]);
    }
  }
  if(cgA < 8) dtin[rA][cgA] = acc[0];
  else dbc_g[((size_t)row0 + rA)*40 + cgA] = acc[0];
  dbc_g[((size_t)row0 + rA)*40 + cgA + 16] = acc[1];
  if(cgA < 8) dbc_g[((size_t)row0 + rA)*40 + cgA + 32] = acc[2];
  for(int u=tid; u<256*8; u+=256) dtw_s[u>>3][u&7] = dtw[u];
  __syncthreads();
  {
    int d = tid;
    float bias = dtb_[d];
    float w8[8];
    #pragma unroll
    for(int k=0;k<8;k++) w8[k] = dtw_s[d][k];
    for(int r2=0;r2<16;r2++){
      float a = bias;
      #pragma unroll
      for(int k=0;k<8;k++) a = fmaf(dtin[r2][k], w8[k], a);
      dt_g[((size_t)row0 + r2)*DI + d] = fsoftplus(a);
    }
  }
}

// ---------- chunked selective scan v3: 8 chunks of 32, block 1024 thr.
// tid = c*128 + gl*16 + n. ylocal & exp cached in regs (fully unrolled).
__global__ __launch_bounds__(1024) void k_scan3(const float* __restrict__ dtb,
      const float* __restrict__ xc, const float* __restrict__ xz,
      const float* __restrict__ dbc, const float* __restrict__ A_log,
      const float* __restrict__ Dp, float* __restrict__ y){
  __shared__ float dt_s[TP][8], xc_s[TP][8];
  __shared__ float Bs[TP][16], Cs[TP][16];
  __shared__ float Eb[8][128], Pb[8][128];
  int tid = threadIdx.x;
  int c = tid >> 7, gl = (tid >> 4) & 7, n = tid & 15;
  int dblk = blockIdx.x & 31, b = blockIdx.x >> 5;
  int d0 = dblk*8;
  size_t rbase = (size_t)b*TP;
  for(int u=tid; u<TP*8; u+=1024){
    int tt = u>>3, gg = u&7;
    size_t r = rbase + tt;
    dt_s[tt][gg] = dtb[r*DI + d0 + gg];
    xc_s[tt][gg] = xc [r*DI + d0 + gg];
  }
  for(int u=tid; u<TP*16; u+=1024){
    int tt = u>>4, nn = u&15;
    size_t r = rbase + tt;
    Bs[tt][nn] = dbc[r*40 + 8  + nn];
    Cs[tt][nn] = dbc[r*40 + 24 + nn];
  }
  __syncthreads();
  int d = d0 + gl;
  float An = -__expf(A_log[d*DS + n]);
  float h = 0.f, dtsum = 0.f;
  int tA = c*32;
  float yloc[32], ev[32];
  #pragma unroll
  for(int i=0;i<32;i++){
    int t = tA + i;
    float dtv = dt_s[t][gl];
    dtsum += dtv;
    float e = __expf(dtv*An);
    ev[i] = e;
    h = fmaf(e, h, dtv*xc_s[t][gl]*Bs[t][n]);
    float p = h*Cs[t][n];
    p += __shfl_xor(p,1); p += __shfl_xor(p,2);
    p += __shfl_xor(p,4); p += __shfl_xor(p,8);
    yloc[i] = p;
  }
  Eb[c][gl*16+n] = h;
  Pb[c][gl*16+n] = __expf(An*dtsum);
  __syncthreads();
  float g = 0.f;
  for(int cp=0; cp<c; cp++)
    g = fmaf(Pb[cp][gl*16+n], g, Eb[cp][gl*16+n]);
  float Dpd = Dp[d];
  #pragma unroll
  for(int i=0;i<32;i++){
    int t = tA + i;
    g *= ev[i];
    float p = g*Cs[t][n];
    p += __shfl_xor(p,1); p += __shfl_xor(p,2);
    p += __shfl_xor(p,4); p += __shfl_xor(p,8);
    float zv = xz[(rbase+t)*512 + DI + d];
    if(n==0){
      float xcv = xc_s[t][gl];
      y[(rbase+t)*DI + d] = (yloc[i] + p + Dpd*xcv) * fsilu(zv);
    }
  }
}

// ---------- out-proj GEMM + residual
__global__ __launch_bounds__(256) void k_out32(const float* __restrict__ A,
    const float* __restrict__ W, float* __restrict__ C){
  __shared__ __align__(16) float As[16][33];
  __shared__ __align__(16) float Ws[16][68];
  int tid = threadIdx.x;
  int n0 = blockIdx.x*64, m0 = blockIdx.y*32;
  int tx = tid&15, ty = tid>>4;
  float acc[2][4] = {};
  for(int k0=0;k0<256;k0+=16){
    if(tid<128){
      int row = tid>>2, cq = (tid&3)*4;
      float4 v = *(const float4*)(A + (size_t)(m0+row)*DI + k0 + cq);
      As[cq+0][row]=v.x; As[cq+1][row]=v.y; As[cq+2][row]=v.z; As[cq+3][row]=v.w;
    } else {
      int u = tid-128; int n = u>>1, cq = (u&1)*8;
      const float* wp = W + (size_t)(n0+n)*DI + k0 + cq;
      float4 v0 = *(const float4*)wp, v1 = *(const float4*)(wp+4);
      Ws[cq+0][n]=v0.x; Ws[cq+1][n]=v0.y; Ws[cq+2][n]=v0.z; Ws[cq+3][n]=v0.w;
      Ws[cq+4][n]=v1.x; Ws[cq+5][n]=v1.y; Ws[cq+6][n]=v1.z; Ws[cq+7][n]=v1.w;
    }
    __syncthreads();
    #pragma unroll
    for(int kk=0;kk<16;kk++){
      float a0 = As[kk][ty*2+0];
      float a1 = As[kk][ty*2+1];
      float4 w4 = *(const float4*)&Ws[kk][tx*4];
      float wv4[4] = {w4.x,w4.y,w4.z,w4.w};
      #pragma unroll
      for(int j=0;j<4;j++){
        acc[0][j] = fmaf(a0, wv4[j], acc[0][j]);
        acc[1][j] = fmaf(a1, wv4[j], acc[1][j]);
      }
    }
    __syncthreads();
  }
  #pragma unroll
  for(int iu=0;iu<2;iu++){
    int m = m0 + ty*2 + iu;
    #pragma unroll
    for(int j=0;j<4;j++){
      int n = n0 + tx*4 + j;
      size_t o = (size_t)m*DM + n;
      C[o] += acc[iu][j];
    }
  }
}

// ---------- masked mean pool + 2-layer classifier. grid = 8, block = 128.
__global__ void k_head(const float* __restrict__ hln, const int* __restrict__ lengths,
                       const float* __restrict__ w1, const float* __restrict__ b1,
                       const float* __restrict__ w2, const float* __restrict__ b2,
                       float* __restrict__ out){
  __shared__ float pooled[DM];
  __shared__ float cbuf[64];
  int b = blockIdx.x, tid = threadIdx.x;
  int tl = lengths[b] >> 1; if(tl < 1) tl = 1;
  float s = 0.f;
  const float* p = hln + (size_t)b*TP*DM + tid;
  for(int t=0;t<tl;t++) s += p[(size_t)t*DM];
  pooled[tid] = s / (float)tl;
  __syncthreads();
  if(tid < 64){
    float a = b1[tid];
    const float* wp = w1 + tid*DM;
    for(int k=0;k<DM;k++) a = fmaf(pooled[k], wp[k], a);
    cbuf[tid] = fsilu(a);
  }
  __syncthreads();
  if(tid < 35){
    float a = b2[tid];
    const float* wp = w2 + tid*64;
    for(int k=0;k<64;k++) a = fmaf(cbuf[k], wp[k], a);
    out[b*35+tid] = a;
  }
}

extern "C" void kernel_launch(void* const* d_in, const int* in_sizes, int n_in,
                              void* d_out, int out_size, void* d_ws, size_t ws_size,
                              hipStream_t stream){
  (void)in_sizes; (void)n_in; (void)out_size; (void)ws_size;
  const float* x        = (const float*)d_in[0];
  const int*   lengths  = (const int*)  d_in[1];
  const float* conv_w1  = (const float*)d_in[2];  const float* conv_b1 = (const float*)d_in[3];
  const float* bn1_s    = (const float*)d_in[4];  const float* bn1_b   = (const float*)d_in[5];
  const float* conv_w2  = (const float*)d_in[6];  const float* conv_b2 = (const float*)d_in[7];
  const float* bn2_s    = (const float*)d_in[8];  const float* bn2_b   = (const float*)d_in[9];
  const float* conv_w3  = (const float*)d_in[10]; const float* conv_b3 = (const float*)d_in[11];
  const float* bn3_s    = (const float*)d_in[12]; const float* bn3_b   = (const float*)d_in[13];
  const float* conv_w4  = (const float*)d_in[14]; const float* conv_b4 = (const float*)d_in[15];
  const float* bn4_s    = (const float*)d_in[16]; const float* bn4_b   = (const float*)d_in[17];
  const float* proj_w   = (const float*)d_in[18]; const float* proj_b  = (const float*)d_in[19];
  const float* proj_ln_s= (const float*)d_in[20]; const float* proj_ln_b=(const float*)d_in[21];
  const float* blk_ln_s = (const float*)d_in[22]; const float* blk_ln_b =(const float*)d_in[23];
  const float* in_w     = (const float*)d_in[24];
  const float* cw       = (const float*)d_in[25]; const float* cbv     = (const float*)d_in[26];
  const float* xp_w     = (const float*)d_in[27];
  const float* dt_w     = (const float*)d_in[28]; const float* dt_b    = (const float*)d_in[29];
  const float* A_log    = (const float*)d_in[30]; const float* Dp      = (const float*)d_in[31];
  const float* out_w    = (const float*)d_in[32];
  const float* pre_ln_s = (const float*)d_in[33]; const float* pre_ln_b= (const float*)d_in[34];
  const float* cls_w1   = (const float*)d_in[35]; const float* cls_b1  = (const float*)d_in[36];
  const float* cls_w2   = (const float*)d_in[37]; const float* cls_b2  = (const float*)d_in[38];

  float* ws   = (float*)d_ws;
  float* R0   = ws;                  // 16,777,216 floats (conv ping)
  float* R1   = R0 + 16777216;       // 16,777,216 floats (conv pong)
  float* xT   = R1 + 16777216;       // 524,288
  float* hbuf = xT + 524288;         // 262,144
  float* lnb  = hbuf + 262144;       // 262,144
  float* xzb  = lnb + 262144;        // 1,048,576
  float* xcb  = xzb + 1048576;       // 524,288
  float* dbcb = xcb + 524288;        // 81,920
  float* dtbb = dbcb + 81920;        // 524,288
  float* yb   = dtbb + 524288;       // 524,288
  float* wt1  = yb + 524288;         // 288
  float* wt2  = wt1 + 288;           // 9,216
  float* wt3  = wt2 + 9216;          // 18,432
  float* wt4  = wt3 + 18432;         // 36,864

  // ---- weight transposes (one launch) to [ci][slot][72]
  k_wt_all<<<254, 256, 0, stream>>>(conv_w1, conv_w2, conv_w3, conv_w4, wt1, wt2, wt3, wt4);

  // ---- frontend
  k_transpose_x<<<2048, 256, 0, stream>>>(x, xT);
  k_conv_t4<1,32,8,1,1><<<8*8*32, 256, 0, stream>>>(xT, wt1, conv_b1, bn1_s, bn1_b, R0, 128, 512);
  k_conv_t4<32,32,8,8,1><<<8*8*32, 256, 0, stream>>>(R0, wt2, conv_b2, bn2_s, bn2_b, R1, 128, 512);
  k_pool2x2<<<(8*32*64*256)/256, 256, 0, stream>>>(R1, R0, 32, 128, 512);
  k_conv_t4<32,64,8,8,2><<<8*4*16*2, 256, 0, stream>>>(R0, wt3, conv_b3, bn3_s, bn3_b, R1, 64, 256);
  k_conv_t4<64,64,8,8,2><<<8*4*16*2, 256, 0, stream>>>(R1, wt4, conv_b4, bn4_s, bn4_b, R0, 64, 256);

  // ---- fused pool(2,1) + projection GEMM -> lnb (raw), then LN+SiLU -> hbuf
  {
    dim3 g(2, 64);
    k_proj<<<g, 256, 0, stream>>>(R0, proj_w, proj_b, lnb);
  }
  k_ln<1><<<2048, 64, 0, stream>>>(lnb, proj_ln_s, proj_ln_b, hbuf);

  // ---- mamba layers
  for(int i=0;i<NL;i++){
    { dim3 g(8, 64);  // fused LN + xz GEMM
      k_lnxz<<<g, 256, 0, stream>>>(hbuf, blk_ln_s + i*DM, blk_ln_b + i*DM,
                                    in_w + (size_t)i*512*DM, xzb); }
    k_xproj16<<<128, 256, 0, stream>>>(xzb, cw + (size_t)i*DI*4, cbv + i*DI,
                                       xp_w + (size_t)i*40*DI, dt_w + (size_t)i*DI*DTR,
                                       dt_b + i*DI, xcb, dbcb, dtbb);
    k_scan3<<<256, 1024, 0, stream>>>(dtbb, xcb, xzb, dbcb, A_log + (size_t)i*DI*DS, Dp + i*DI, yb);
    { dim3 g(2, 64);  // out-proj + residual
      k_out32<<<g, 256, 0, stream>>>(yb, out_w + (size_t)i*DM*DI, hbuf); }
  }

  // ---- head
  k_ln<0><<<2048, 64, 0, stream>>>(hbuf, pre_ln_s, pre_ln_b, lnb);
  k_head<<<8, 128, 0, stream>>>(lnb, lengths, cls_w1, cls_b1, cls_w2, cls_b2, (float*)d_out);
}

// Round 6
// 1278.898 us; speedup vs baseline: 3.2579x; 1.1554x over previous
//
#include <hip/hip_runtime.h>
#include <math.h>

#define B_ 8
#define T_ 512
#define FEAT_ 128
#define TP 256          // T' after frontend
#define DM 128          // d_model
#define DI 256          // d_inner
#define DS 16           // d_state
#define DTR 8
#define NL 10

__device__ __forceinline__ float fsilu(float x){ return x / (1.f + __expf(-x)); }
__device__ __forceinline__ float fsoftplus(float x){ return (x > 20.f) ? x : log1pf(__expf(x)); }

// ---------- transpose x [8,512,128] -> xT [8,128,512]
__global__ void k_transpose_x(const float* __restrict__ x, float* __restrict__ xT){
  int idx = blockIdx.x*256 + threadIdx.x;
  if(idx >= B_*FEAT_*T_) return;
  int t = idx % T_; int f = (idx/T_) % FEAT_; int b = idx/(T_*FEAT_);
  xT[idx] = x[((size_t)b*T_ + t)*FEAT_ + f];
}

// ---------- all 4 conv-weight transposes in one launch.
// out layout: [ci][slot][72] where slot = co/8, within = (co%8)*9 + k
__device__ __forceinline__ void wt_one(const float* __restrict__ w, float* __restrict__ o,
                                       int idx, int CO, int CIN){
  int k = idx % 9; int ci = (idx/9) % CIN; int co = idx/(9*CIN);
  o[((size_t)(ci*(CO>>3) + (co>>3)))*72 + (co&7)*9 + k] = w[idx];
}
__global__ void k_wt_all(const float* __restrict__ w1, const float* __restrict__ w2,
                         const float* __restrict__ w3, const float* __restrict__ w4,
                         float* __restrict__ o1, float* __restrict__ o2,
                         float* __restrict__ o3, float* __restrict__ o4){
  int idx = blockIdx.x*256 + threadIdx.x;
  if(idx < 288){ wt_one(w1, o1, idx, 32, 1); return; }
  idx -= 288;
  if(idx < 9216){ wt_one(w2, o2, idx, 32, 32); return; }
  idx -= 9216;
  if(idx < 18432){ wt_one(w3, o3, idx, 64, 32); return; }
  idx -= 18432;
  if(idx < 36864){ wt_one(w4, o4, idx, 64, 64); return; }
}

// ---------- tiled direct 3x3 SAME conv + folded BN + SiLU. v5:
// lane map r=lane&15, cg=lane>>4 -> each 8-lane LDS phase group spans all 8
// bank-quads ((5r+cg)mod8 is a permutation) => ds_read_b128 conflict-free.
template<int CIN, int CO, int CPW, int CIG, int COG>
__global__ __launch_bounds__(256) void k_conv_t4(const float* __restrict__ in,
     const float* __restrict__ wt, const float* __restrict__ cb,
     const float* __restrict__ bs, const float* __restrict__ bb,
     float* __restrict__ out, int H, int W){
  constexpr int NS = CO/CPW;            // total wave-slots
  __shared__ __align__(16) float tile[CIG*360];   // [CIG][18][20]
  int tid = threadIdx.x;
  int lane = tid & 63;
  int wav = __builtin_amdgcn_readfirstlane(tid >> 6);
  int wpr = W >> 4, hpr = H >> 4;
  int idx = blockIdx.x;
  int cog = idx % COG; idx /= COG;
  int tj = idx % wpr; idx /= wpr;
  int ti = idx % hpr; int b = idx / hpr;
  int i0 = ti*16, j0 = tj*16;
  int r = lane & 15, cg = lane >> 4;
  int wslot = cog*4 + wav;
  const float* wbase = wt + (size_t)wslot*72;
  float acc[CPW][4] = {};
  for(int cig = 0; cig < CIN; cig += CIG){
    __syncthreads();
    for(int u = tid; u < CIG*324; u += 256){
      int ci = u / 324; int rem = u - ci*324; int rr = rem / 18; int cc = rem - rr*18;
      int gi = i0 - 1 + rr, gj = j0 - 1 + cc;
      float v = 0.f;
      if(gi >= 0 && gi < H && gj >= 0 && gj < W)
        v = in[((size_t)(b*CIN + cig + ci)*H + gi)*W + gj];
      tile[ci*360 + rr*20 + cc] = v;
    }
    __syncthreads();
    for(int ci = 0; ci < CIG; ci++){
      const float4* wp4 = (const float4*)(wbase + (size_t)(cig+ci)*(NS*72));
      float4 w4q[18];
      #pragma unroll
      for(int q=0;q<18;q++) w4q[q] = wp4[q];
      const float* wf = (const float*)w4q;
      #pragma unroll
      for(int kh=0;kh<3;kh++){
        float4 a = *(const float4*)&tile[ci*360 + (r+kh)*20 + cg*4];
        float4 bv = *(const float4*)&tile[ci*360 + (r+kh)*20 + cg*4 + 4];
        float v[6] = {a.x,a.y,a.z,a.w,bv.x,bv.y};
        #pragma unroll
        for(int co=0;co<CPW;co++){
          #pragma unroll
          for(int kw=0;kw<3;kw++){
            float wv = wf[co*9 + kh*3 + kw];
            #pragma unroll
            for(int u2=0;u2<4;u2++)
              acc[co][u2] = fmaf(wv, v[kw+u2], acc[co][u2]);
          }
        }
      }
    }
  }
  int i = i0 + r;
  #pragma unroll
  for(int co=0; co<CPW; co++){
    int c = cog*(4*CPW) + wav*CPW + co;
    float s = bs[c], bias = cb[c]*s + bb[c];
    float4 o;
    o.x = fsilu(acc[co][0]*s + bias);
    o.y = fsilu(acc[co][1]*s + bias);
    o.z = fsilu(acc[co][2]*s + bias);
    o.w = fsilu(acc[co][3]*s + bias);
    *(float4*)&out[((size_t)(b*CO + c)*H + i)*W + j0 + cg*4] = o;
  }
}

// ---------- 2x2 max pool stride 2
__global__ void k_pool2x2(const float* __restrict__ in, float* __restrict__ out,
                          int C, int Hi, int Wi){
  int Ho = Hi>>1, Wo = Wi>>1;
  int total = B_*C*Ho*Wo;
  int idx = blockIdx.x*256 + threadIdx.x;
  if(idx >= total) return;
  int j = idx % Wo; int i = (idx/Wo)%Ho; int c = (idx/(Wo*Ho))%C; int b = idx/(Wo*Ho*C);
  const float* p = in + (((size_t)(b*C+c)*Hi + 2*i)*Wi + 2*j);
  out[idx] = fmaxf(fmaxf(p[0], p[1]), fmaxf(p[Wi], p[Wi+1]));
}

// ---------- fused (2,1)-maxpool + proj GEMM, split-K x8.
// grid (2, 64, 8); partials -> pbuf[kc][2048][128]. No bias here.
__global__ __launch_bounds__(256) void k_proj(const float* __restrict__ R0,
    const float* __restrict__ W, float* __restrict__ pbuf){
  __shared__ __align__(16) float As[16][33];
  __shared__ __align__(16) float Ws[16][68];
  int tid = threadIdx.x;
  int n0 = blockIdx.x*64, m0 = blockIdx.y*32;
  int kc = blockIdx.z;
  int b = m0 >> 8;
  int t_base = m0 & 255;
  int tx = tid&15, ty = tid>>4;
  float acc[2][4] = {};
  for(int k0=0; k0<256; k0+=16){
    int kg0 = kc*256 + k0;
    if(tid < 128){
      int row = tid>>2, cq = (tid&3)*4;
      #pragma unroll
      for(int c2=0;c2<4;c2++){
        int k = kg0 + cq + c2;
        int c = k>>5, hh = k&31;
        const float* p = R0 + (((size_t)(b*64+c)*64 + 2*hh)*256 + t_base + row);
        As[cq+c2][row] = fmaxf(p[0], p[256]);
      }
    } else {
      int u = tid - 128; int n = u>>1, cq = (u&1)*8;
      const float* wp = W + (size_t)(n0+n)*2048 + kg0 + cq;
      float4 v0 = *(const float4*)wp, v1 = *(const float4*)(wp+4);
      Ws[cq+0][n]=v0.x; Ws[cq+1][n]=v0.y; Ws[cq+2][n]=v0.z; Ws[cq+3][n]=v0.w;
      Ws[cq+4][n]=v1.x; Ws[cq+5][n]=v1.y; Ws[cq+6][n]=v1.z; Ws[cq+7][n]=v1.w;
    }
    __syncthreads();
    #pragma unroll
    for(int kk=0;kk<16;kk++){
      float a0 = As[kk][ty*2+0];
      float a1 = As[kk][ty*2+1];
      float4 w4 = *(const float4*)&Ws[kk][tx*4];
      float wv4[4] = {w4.x,w4.y,w4.z,w4.w};
      #pragma unroll
      for(int j=0;j<4;j++){
        acc[0][j] = fmaf(a0, wv4[j], acc[0][j]);
        acc[1][j] = fmaf(a1, wv4[j], acc[1][j]);
      }
    }
    __syncthreads();
  }
  float* pb = pbuf + (size_t)kc*2048*DM;
  #pragma unroll
  for(int iu=0;iu<2;iu++){
    int m = m0 + ty*2 + iu;
    #pragma unroll
    for(int j=0;j<4;j++){
      int n = n0 + tx*4 + j;
      pb[(size_t)m*DM + n] = acc[iu][j];
    }
  }
}

// ---------- reduce 8 split-K partials + bias + LN + SiLU -> hbuf. 1 wave/row.
__global__ void k_lnp(const float* __restrict__ pbuf, const float* __restrict__ bias,
                      const float* __restrict__ g, const float* __restrict__ b,
                      float* __restrict__ out){
  int row = blockIdx.x;
  int t = threadIdx.x; // 64
  float v0 = bias[t], v1 = bias[t+64];
  #pragma unroll
  for(int kc=0;kc<8;kc++){
    const float* p = pbuf + ((size_t)kc*2048 + row)*DM;
    v0 += p[t]; v1 += p[t+64];
  }
  float s = v0 + v1;
  #pragma unroll
  for(int m=32;m>=1;m>>=1) s += __shfl_xor(s, m);
  float mean = s * (1.f/128.f);
  float e0 = v0-mean, e1 = v1-mean;
  float q = e0*e0 + e1*e1;
  #pragma unroll
  for(int m=32;m>=1;m>>=1) q += __shfl_xor(q, m);
  float inv = rsqrtf(q*(1.f/128.f) + 1e-5f);
  float o0 = fsilu(e0*inv*g[t] + b[t]);
  float o1 = fsilu(e1*inv*g[t+64] + b[t+64]);
  float* po = out + (size_t)row*DM;
  po[t] = o0; po[t+64] = o1;
}

// ---------- LayerNorm over last dim (128), optional SiLU. 1 wave per row.
template<int SILU>
__global__ void k_ln(const float* __restrict__ in, const float* __restrict__ g,
                     const float* __restrict__ b, float* __restrict__ out){
  int row = blockIdx.x;
  int t = threadIdx.x; // 64
  const float* p = in + (size_t)row*DM;
  float v0 = p[t], v1 = p[t+64];
  float s = v0 + v1;
  #pragma unroll
  for(int m=32;m>=1;m>>=1) s += __shfl_xor(s, m);
  float mean = s * (1.f/128.f);
  float e0 = v0-mean, e1 = v1-mean;
  float q = e0*e0 + e1*e1;
  #pragma unroll
  for(int m=32;m>=1;m>>=1) q += __shfl_xor(q, m);
  float inv = rsqrtf(q*(1.f/128.f) + 1e-5f);
  float o0 = e0*inv*g[t] + b[t];
  float o1 = e1*inv*g[t+64] + b[t+64];
  if(SILU){ o0 = fsilu(o0); o1 = fsilu(o1); }
  float* po = out + (size_t)row*DM;
  po[t] = o0; po[t+64] = o1;
}

// ---------- fused LN + xz GEMM: xz[m][n] = LN(hbuf[m]) @ in_w[n]^T.
__global__ __launch_bounds__(256) void k_lnxz(const float* __restrict__ hbuf,
    const float* __restrict__ g, const float* __restrict__ bb,
    const float* __restrict__ W, float* __restrict__ out){
  __shared__ __align__(16) float lns[32][132];
  __shared__ __align__(16) float Ws[16][68];
  int tid = threadIdx.x;
  int n0 = blockIdx.x*64, m0 = blockIdx.y*32;
  for(int u=tid; u<1024; u+=256){
    int row = u>>5, c4 = (u&31)*4;
    float4 v = *(const float4*)(hbuf + (size_t)(m0+row)*DM + c4);
    lns[row][c4] = v.x; lns[row][c4+1] = v.y; lns[row][c4+2] = v.z; lns[row][c4+3] = v.w;
  }
  __syncthreads();
  {
    int lane = tid & 63, wv = tid >> 6;
    for(int rr = wv; rr < 32; rr += 4){
      float v0 = lns[rr][lane], v1 = lns[rr][lane+64];
      float s = v0+v1;
      #pragma unroll
      for(int mm=32;mm>=1;mm>>=1) s += __shfl_xor(s,mm);
      float mean = s*(1.f/128.f);
      float e0 = v0-mean, e1 = v1-mean;
      float q = e0*e0+e1*e1;
      #pragma unroll
      for(int mm=32;mm>=1;mm>>=1) q += __shfl_xor(q,mm);
      float inv = rsqrtf(q*(1.f/128.f)+1e-5f);
      lns[rr][lane]    = e0*inv*g[lane] + bb[lane];
      lns[rr][lane+64] = e1*inv*g[lane+64] + bb[lane+64];
    }
  }
  __syncthreads();
  int tx = tid&15, ty = tid>>4;
  float acc[2][4] = {};
  for(int k0=0;k0<128;k0+=16){
    {
      int n = tid>>2, c4 = (tid&3)*4;
      float4 v = *(const float4*)(W + (size_t)(n0+n)*DM + k0 + c4);
      Ws[c4+0][n]=v.x; Ws[c4+1][n]=v.y; Ws[c4+2][n]=v.z; Ws[c4+3][n]=v.w;
    }
    __syncthreads();
    #pragma unroll
    for(int kk=0;kk<16;kk++){
      float a0 = lns[ty*2+0][k0+kk];
      float a1 = lns[ty*2+1][k0+kk];
      float4 w4 = *(const float4*)&Ws[kk][tx*4];
      float wv4[4] = {w4.x,w4.y,w4.z,w4.w};
      #pragma unroll
      for(int j=0;j<4;j++){
        acc[0][j] = fmaf(a0, wv4[j], acc[0][j]);
        acc[1][j] = fmaf(a1, wv4[j], acc[1][j]);
      }
    }
    __syncthreads();
  }
  #pragma unroll
  for(int iu=0;iu<2;iu++){
    int m = m0 + ty*2 + iu;
    float* po = out + (size_t)m*512 + n0 + tx*4;
    #pragma unroll
    for(int j=0;j<4;j++) po[j] = acc[iu][j];
  }
}

// ---------- fused: causal dwconv(4)+SiLU -> dbc GEMM -> dt GEMM+softplus.
// 8 rows/block, grid 256, 256 thr.
__global__ __launch_bounds__(256) void k_xproj8(const float* __restrict__ xz,
    const float* __restrict__ cw, const float* __restrict__ cb,
    const float* __restrict__ xpw, const float* __restrict__ dtw,
    const float* __restrict__ dtb_, float* __restrict__ xc_g,
    float* __restrict__ dbc_g, float* __restrict__ dt_g){
  __shared__ float xzs[11][64];
  __shared__ float As[64][9];
  __shared__ float Wp[64][41];
  __shared__ float dtin[8][9];
  __shared__ float dtw_s[256][9];
  int tid = threadIdx.x;
  int row0 = blockIdx.x*8; int b = row0 >> 8; int t0 = row0 & 255;
  int rA = tid & 7, cgA = tid >> 3;       // dbc: 8 rows x 32 col-groups
  int dlC = tid & 63, rqC = tid >> 6;     // conv: 64 d x 4 quads (2 rows each)
  float acc0 = 0.f, acc1 = 0.f;
  for(int ch=0; ch<4; ch++){
    int d0 = ch*64;
    __syncthreads();
    for(int u=tid; u<11*64; u+=256){
      int rr = u>>6, dl = u&63;
      int t = t0 + rr - 3;
      xzs[rr][dl] = (t >= 0) ? xz[((size_t)(b*TP)+t)*512 + d0 + dl] : 0.f;
    }
    for(int u=tid; u<40*64; u+=256){
      int nn = u>>6, dk = u&63;
      Wp[dk][nn] = xpw[(size_t)nn*DI + d0 + dk];
    }
    __syncthreads();
    {
      float cw0 = cw[(d0+dlC)*4+0], cw1 = cw[(d0+dlC)*4+1];
      float cw2 = cw[(d0+dlC)*4+2], cw3 = cw[(d0+dlC)*4+3];
      float cbv = cb[d0+dlC];
      #pragma unroll
      for(int i=0;i<2;i++){
        int rr = rqC*2 + i;
        float a = cbv;
        a = fmaf(cw0, xzs[rr+0][dlC], a);
        a = fmaf(cw1, xzs[rr+1][dlC], a);
        a = fmaf(cw2, xzs[rr+2][dlC], a);
        a = fmaf(cw3, xzs[rr+3][dlC], a);
        float v = fsilu(a);
        As[dlC][rr] = v;
        xc_g[((size_t)row0 + rr)*DI + d0 + dlC] = v;
      }
    }
    __syncthreads();
    for(int dk=0; dk<64; dk++){
      float a = As[dk][rA];
      acc0 = fmaf(a, Wp[dk][cgA], acc0);
      if(cgA < 8) acc1 = fmaf(a, Wp[dk][cgA+32], acc1);
    }
  }
  if(cgA < 8){
    dtin[rA][cgA] = acc0;
    dbc_g[((size_t)row0 + rA)*40 + cgA + 32] = acc1;
  } else {
    dbc_g[((size_t)row0 + rA)*40 + cgA] = acc0;
  }
  for(int u=tid; u<256*8; u+=256) dtw_s[u>>3][u&7] = dtw[u];
  __syncthreads();
  {
    int d = tid;
    float bias = dtb_[d];
    float w8[8];
    #pragma unroll
    for(int k=0;k<8;k++) w8[k] = dtw_s[d][k];
    #pragma unroll
    for(int r2=0;r2<8;r2++){
      float a = bias;
      #pragma unroll
      for(int k=0;k<8;k++) a = fmaf(dtin[r2][k], w8[k], a);
      dt_g[((size_t)row0 + r2)*DI + d] = fsoftplus(a);
    }
  }
}

// ---------- chunked selective scan v3: 8 chunks of 32, block 1024 thr.
__global__ __launch_bounds__(1024) void k_scan3(const float* __restrict__ dtb,
      const float* __restrict__ xc, const float* __restrict__ xz,
      const float* __restrict__ dbc, const float* __restrict__ A_log,
      const float* __restrict__ Dp, float* __restrict__ y){
  __shared__ float dt_s[TP][8], xc_s[TP][8];
  __shared__ float Bs[TP][16], Cs[TP][16];
  __shared__ float Eb[8][128], Pb[8][128];
  int tid = threadIdx.x;
  int c = tid >> 7, gl = (tid >> 4) & 7, n = tid & 15;
  int dblk = blockIdx.x & 31, b = blockIdx.x >> 5;
  int d0 = dblk*8;
  size_t rbase = (size_t)b*TP;
  for(int u=tid; u<TP*8; u+=1024){
    int tt = u>>3, gg = u&7;
    size_t r = rbase + tt;
    dt_s[tt][gg] = dtb[r*DI + d0 + gg];
    xc_s[tt][gg] = xc [r*DI + d0 + gg];
  }
  for(int u=tid; u<TP*16; u+=1024){
    int tt = u>>4, nn = u&15;
    size_t r = rbase + tt;
    Bs[tt][nn] = dbc[r*40 + 8  + nn];
    Cs[tt][nn] = dbc[r*40 + 24 + nn];
  }
  __syncthreads();
  int d = d0 + gl;
  float An = -__expf(A_log[d*DS + n]);
  float h = 0.f, dtsum = 0.f;
  int tA = c*32;
  float yloc[32], ev[32];
  #pragma unroll
  for(int i=0;i<32;i++){
    int t = tA + i;
    float dtv = dt_s[t][gl];
    dtsum += dtv;
    float e = __expf(dtv*An);
    ev[i] = e;
    h = fmaf(e, h, dtv*xc_s[t][gl]*Bs[t][n]);
    float p = h*Cs[t][n];
    p += __shfl_xor(p,1); p += __shfl_xor(p,2);
    p += __shfl_xor(p,4); p += __shfl_xor(p,8);
    yloc[i] = p;
  }
  Eb[c][gl*16+n] = h;
  Pb[c][gl*16+n] = __expf(An*dtsum);
  __syncthreads();
  float g = 0.f;
  for(int cp=0; cp<c; cp++)
    g = fmaf(Pb[cp][gl*16+n], g, Eb[cp][gl*16+n]);
  float Dpd = Dp[d];
  #pragma unroll
  for(int i=0;i<32;i++){
    int t = tA + i;
    g *= ev[i];
    float p = g*Cs[t][n];
    p += __shfl_xor(p,1); p += __shfl_xor(p,2);
    p += __shfl_xor(p,4); p += __shfl_xor(p,8);
    if(n==0){
      float zv = xz[(rbase+t)*512 + DI + d];
      float xcv = xc_s[t][gl];
      y[(rbase+t)*DI + d] = (yloc[i] + p + Dpd*xcv) * fsilu(zv);
    }
  }
}

// ---------- out-proj GEMM + residual, 16-row tiles: grid (2, 128).
__global__ __launch_bounds__(256) void k_out16(const float* __restrict__ A,
    const float* __restrict__ W, float* __restrict__ C){
  __shared__ float As[16][17];
  __shared__ __align__(16) float Ws[16][68];
  int tid = threadIdx.x;
  int n0 = blockIdx.x*64, m0 = blockIdx.y*16;
  int tx = tid&15, ty = tid>>4;
  float acc[4] = {};
  for(int k0=0;k0<256;k0+=16){
    {
      int row = tid>>4, kk = tid&15;
      As[kk][row] = A[(size_t)(m0+row)*DI + k0 + kk];
    }
    {
      int n = tid>>2, cq = (tid&3)*4;
      float4 v = *(const float4*)(W + (size_t)(n0+n)*DI + k0 + cq);
      Ws[cq+0][n]=v.x; Ws[cq+1][n]=v.y; Ws[cq+2][n]=v.z; Ws[cq+3][n]=v.w;
    }
    __syncthreads();
    #pragma unroll
    for(int kk=0;kk<16;kk++){
      float a0 = As[kk][ty];
      float4 w4 = *(const float4*)&Ws[kk][tx*4];
      acc[0] = fmaf(a0, w4.x, acc[0]);
      acc[1] = fmaf(a0, w4.y, acc[1]);
      acc[2] = fmaf(a0, w4.z, acc[2]);
      acc[3] = fmaf(a0, w4.w, acc[3]);
    }
    __syncthreads();
  }
  int m = m0 + ty;
  float* cp = &C[(size_t)m*DM + n0 + tx*4];
  cp[0] += acc[0]; cp[1] += acc[1]; cp[2] += acc[2]; cp[3] += acc[3];
}

// ---------- masked mean pool + 2-layer classifier. grid = 8, block = 128.
__global__ void k_head(const float* __restrict__ hln, const int* __restrict__ lengths,
                       const float* __restrict__ w1, const float* __restrict__ b1,
                       const float* __restrict__ w2, const float* __restrict__ b2,
                       float* __restrict__ out){
  __shared__ float pooled[DM];
  __shared__ float cbuf[64];
  int b = blockIdx.x, tid = threadIdx.x;
  int tl = lengths[b] >> 1; if(tl < 1) tl = 1;
  float s = 0.f;
  const float* p = hln + (size_t)b*TP*DM + tid;
  for(int t=0;t<tl;t++) s += p[(size_t)t*DM];
  pooled[tid] = s / (float)tl;
  __syncthreads();
  if(tid < 64){
    float a = b1[tid];
    const float* wp = w1 + tid*DM;
    for(int k=0;k<DM;k++) a = fmaf(pooled[k], wp[k], a);
    cbuf[tid] = fsilu(a);
  }
  __syncthreads();
  if(tid < 35){
    float a = b2[tid];
    const float* wp = w2 + tid*64;
    for(int k=0;k<64;k++) a = fmaf(cbuf[k], wp[k], a);
    out[b*35+tid] = a;
  }
}

extern "C" void kernel_launch(void* const* d_in, const int* in_sizes, int n_in,
                              void* d_out, int out_size, void* d_ws, size_t ws_size,
                              hipStream_t stream){
  (void)in_sizes; (void)n_in; (void)out_size; (void)ws_size;
  const float* x        = (const float*)d_in[0];
  const int*   lengths  = (const int*)  d_in[1];
  const float* conv_w1  = (const float*)d_in[2];  const float* conv_b1 = (const float*)d_in[3];
  const float* bn1_s    = (const float*)d_in[4];  const float* bn1_b   = (const float*)d_in[5];
  const float* conv_w2  = (const float*)d_in[6];  const float* conv_b2 = (const float*)d_in[7];
  const float* bn2_s    = (const float*)d_in[8];  const float* bn2_b   = (const float*)d_in[9];
  const float* conv_w3  = (const float*)d_in[10]; const float* conv_b3 = (const float*)d_in[11];
  const float* bn3_s    = (const float*)d_in[12]; const float* bn3_b   = (const float*)d_in[13];
  const float* conv_w4  = (const float*)d_in[14]; const float* conv_b4 = (const float*)d_in[15];
  const float* bn4_s    = (const float*)d_in[16]; const float* bn4_b   = (const float*)d_in[17];
  const float* proj_w   = (const float*)d_in[18]; const float* proj_b  = (const float*)d_in[19];
  const float* proj_ln_s= (const float*)d_in[20]; const float* proj_ln_b=(const float*)d_in[21];
  const float* blk_ln_s = (const float*)d_in[22]; const float* blk_ln_b =(const float*)d_in[23];
  const float* in_w     = (const float*)d_in[24];
  const float* cw       = (const float*)d_in[25]; const float* cbv     = (const float*)d_in[26];
  const float* xp_w     = (const float*)d_in[27];
  const float* dt_w     = (const float*)d_in[28]; const float* dt_b    = (const float*)d_in[29];
  const float* A_log    = (const float*)d_in[30]; const float* Dp      = (const float*)d_in[31];
  const float* out_w    = (const float*)d_in[32];
  const float* pre_ln_s = (const float*)d_in[33]; const float* pre_ln_b= (const float*)d_in[34];
  const float* cls_w1   = (const float*)d_in[35]; const float* cls_b1  = (const float*)d_in[36];
  const float* cls_w2   = (const float*)d_in[37]; const float* cls_b2  = (const float*)d_in[38];

  float* ws   = (float*)d_ws;
  float* R0   = ws;                  // 16,777,216 floats (conv ping)
  float* R1   = R0 + 16777216;       // 16,777,216 floats (conv pong / proj partials)
  float* xT   = R1 + 16777216;       // 524,288
  float* hbuf = xT + 524288;         // 262,144
  float* lnb  = hbuf + 262144;       // 262,144
  float* xzb  = lnb + 262144;        // 1,048,576
  float* xcb  = xzb + 1048576;       // 524,288
  float* dbcb = xcb + 524288;        // 81,920
  float* dtbb = dbcb + 81920;        // 524,288
  float* yb   = dtbb + 524288;       // 524,288
  float* wt1  = yb + 524288;         // 288
  float* wt2  = wt1 + 288;           // 9,216
  float* wt3  = wt2 + 9216;          // 18,432
  float* wt4  = wt3 + 18432;         // 36,864

  // ---- weight transposes (one launch) to [ci][slot][72]
  k_wt_all<<<254, 256, 0, stream>>>(conv_w1, conv_w2, conv_w3, conv_w4, wt1, wt2, wt3, wt4);

  // ---- frontend
  k_transpose_x<<<2048, 256, 0, stream>>>(x, xT);
  k_conv_t4<1,32,8,1,1><<<8*8*32, 256, 0, stream>>>(xT, wt1, conv_b1, bn1_s, bn1_b, R0, 128, 512);
  k_conv_t4<32,32,8,8,1><<<8*8*32, 256, 0, stream>>>(R0, wt2, conv_b2, bn2_s, bn2_b, R1, 128, 512);
  k_pool2x2<<<(8*32*64*256)/256, 256, 0, stream>>>(R1, R0, 32, 128, 512);
  k_conv_t4<32,64,8,8,2><<<8*4*16*2, 256, 0, stream>>>(R0, wt3, conv_b3, bn3_s, bn3_b, R1, 64, 256);
  k_conv_t4<64,64,8,8,2><<<8*4*16*2, 256, 0, stream>>>(R1, wt4, conv_b4, bn4_s, bn4_b, R0, 64, 256);

  // ---- fused pool(2,1) + projection GEMM (split-K x8) -> partials in R1
  {
    dim3 g(2, 64, 8);
    k_proj<<<g, 256, 0, stream>>>(R0, proj_w, R1);
  }
  k_lnp<<<2048, 64, 0, stream>>>(R1, proj_b, proj_ln_s, proj_ln_b, hbuf);

  // ---- mamba layers
  for(int i=0;i<NL;i++){
    { dim3 g(8, 64);  // fused LN + xz GEMM
      k_lnxz<<<g, 256, 0, stream>>>(hbuf, blk_ln_s + i*DM, blk_ln_b + i*DM,
                                    in_w + (size_t)i*512*DM, xzb); }
    k_xproj8<<<256, 256, 0, stream>>>(xzb, cw + (size_t)i*DI*4, cbv + i*DI,
                                      xp_w + (size_t)i*40*DI, dt_w + (size_t)i*DI*DTR,
                                      dt_b + i*DI, xcb, dbcb, dtbb);
    k_scan3<<<256, 1024, 0, stream>>>(dtbb, xcb, xzb, dbcb, A_log + (size_t)i*DI*DS, Dp + i*DI, yb);
    { dim3 g(2, 128);  // out-proj + residual
      k_out16<<<g, 256, 0, stream>>>(yb, out_w + (size_t)i*DM*DI, hbuf); }
  }

  // ---- head
  k_ln<0><<<2048, 64, 0, stream>>>(hbuf, pre_ln_s, pre_ln_b, lnb);
  k_head<<<8, 128, 0, stream>>>(lnb, lengths, cls_w1, cls_b1, cls_w2, cls_b2, (float*)d_out);
}